// Round 3
// baseline (872.321 us; speedup 1.0000x reference)
//
#include <hip/hip_runtime.h>
#include <hip/hip_bf16.h>

typedef __hip_bfloat16 bf16;
typedef short s16x8 __attribute__((ext_vector_type(8)));
typedef float f32x4 __attribute__((ext_vector_type(4)));

#define N_NODES 50000
#define NPAD    50048          // multiple of 64
#define E_EDGES 600000
#define HID     128
#define HEADS   4
#define SCAN_B  196            // ceil(NPAD/256)

// ---- float -> bf16 bits (RNE), finite inputs only ----
__device__ __forceinline__ unsigned short f2bf_bits(float f) {
  unsigned u = __float_as_uint(f);
  u += 0x7fffu + ((u >> 16) & 1u);
  return (unsigned short)(u >> 16);
}
__device__ __forceinline__ float bf2f(unsigned short b) {
  return __uint_as_float(((unsigned)b) << 16);
}
// packed-dword bf16 pair -> floats (1 op each)
__device__ __forceinline__ float lo_f(unsigned v) { return __uint_as_float(v << 16); }
__device__ __forceinline__ float hi_f(unsigned v) { return __uint_as_float(v & 0xffff0000u); }

// lrelu(x) = max(x, 0.2x) for slope in (0,1): 2 VALU ops
__device__ __forceinline__ float lrelu(float v) { return fmaxf(v, 0.2f * v); }

// ---- runtime dtype detection + zero (fused: one dispatch) ----
__global__ __launch_bounds__(256) void detect_zero_kernel(const unsigned short* __restrict__ xb,
                                                          const int* __restrict__ ei,
                                                          int* __restrict__ flags,
                                                          int* __restrict__ zp, int nz) {
  int t = threadIdx.x;
  int i = blockIdx.x * 256 + t;
  if (i < nz) zp[i] = 0;
  if (blockIdx.x == 0) {
    __shared__ int cnt[2];
    if (t < 2) cnt[t] = 0;
    __syncthreads();
    unsigned short v = xb[2 * t];
    int ex = (v >> 7) & 0xFF;
    if (ex < 119 || ex > 135) atomicAdd(&cnt[0], 1);
    if (ei[2 * t + 1] != 0) atomicAdd(&cnt[1], 1);
    __syncthreads();
    if (t == 0) {
      flags[0] = (cnt[0] > 64) ? 1 : 0;
      flags[1] = (cnt[1] == 0) ? 1 : 0;
    }
  }
}

// ---- index conversion + degree histogram ----
__global__ __launch_bounds__(256) void cvt_idx_hist_kernel(const int* __restrict__ eidx,
                                                           const int* __restrict__ etype,
                                                           int* __restrict__ dstA, int* __restrict__ pk,
                                                           int* __restrict__ deg,
                                                           const int* __restrict__ flags) {
  int e = blockIdx.x * 256 + threadIdx.x;
  if (e >= E_EDGES) return;
  int s, d, r;
  if (flags[1]) {
    const long long* e64 = (const long long*)eidx;
    const long long* t64 = (const long long*)etype;
    s = (int)e64[e]; d = (int)e64[E_EDGES + e]; r = (int)t64[e];
  } else {
    s = eidx[e]; d = eidx[E_EDGES + e]; r = etype[e];
  }
  dstA[e] = d;
  pk[e] = s | (r << 16);
  atomicAdd(&deg[d], 1);
}

// ---- degree-class bucketing: deg<=16 -> nq (quad kernel), else nw ----
__global__ __launch_bounds__(256) void bucket_kernel(const int* __restrict__ deg,
                                                     int* __restrict__ bcnt,
                                                     int* __restrict__ nq,
                                                     int* __restrict__ nw) {
  int n = blockIdx.x * 256 + threadIdx.x;
  if (n >= N_NODES) return;
  int d = deg[n];
  if (d <= 16) nq[atomicAdd(&bcnt[0], 1)] = n;
  else         nw[atomicAdd(&bcnt[1], 1)] = n;
}

// ---- float-tensor -> bf16 bits, 8 elems/thread (vectorized) ----
__global__ __launch_bounds__(256) void cvt_xb_kernel(const void* __restrict__ src,
                                                     unsigned short* __restrict__ dst, int n8,
                                                     const int* __restrict__ flags) {
  int i = blockIdx.x * 256 + threadIdx.x;
  if (i >= n8) return;
  if (flags[0]) {
    const float4* s4 = (const float4*)src;
    float4 a = s4[2 * i], b = s4[2 * i + 1];
    s16x8 o;
    o[0] = (short)f2bf_bits(a.x); o[1] = (short)f2bf_bits(a.y);
    o[2] = (short)f2bf_bits(a.z); o[3] = (short)f2bf_bits(a.w);
    o[4] = (short)f2bf_bits(b.x); o[5] = (short)f2bf_bits(b.y);
    o[6] = (short)f2bf_bits(b.z); o[7] = (short)f2bf_bits(b.w);
    *(s16x8*)(dst + (size_t)i * 8) = o;
  } else {
    *(s16x8*)(dst + (size_t)i * 8) = ((const s16x8*)src)[i];
  }
}

// ---- W (both layers) -> bf16 N-major [l][r][o][i] ----
__global__ __launch_bounds__(256) void cvt_wt_kernel(const void* __restrict__ src0,
                                                     const void* __restrict__ src1,
                                                     unsigned short* __restrict__ dst,
                                                     const int* __restrict__ flags) {
  int idx = blockIdx.x * 256 + threadIdx.x;
  if (idx >= 2 * 2 * HID * HID) return;
  int l = idx >> 15, rem = idx & 32767;
  int r = rem >> 14, i = (rem >> 7) & 127, o = rem & 127;
  const void* src = l ? src1 : src0;
  unsigned short b;
  if (flags[0]) b = f2bf_bits(((const float*)src)[rem]);
  else          b = ((const unsigned short*)src)[rem];
  dst[(size_t)l * 2 * HID * HID + ((size_t)r * HID + o) * HID + i] = b;
}

// ---- small params -> fp32 block ----
struct P8 { const void* src[8]; int dstoff[8]; int n[8]; };
__global__ __launch_bounds__(256) void cvt_params_kernel(P8 tab, float* __restrict__ base,
                                                         const int* __restrict__ flags) {
  const int f = flags[0];
  for (int k = 0; k < 8; ++k) {
    int n = tab.n[k];
    for (int i = blockIdx.x * 256 + threadIdx.x; i < n; i += gridDim.x * 256) {
      float v = f ? ((const float*)tab.src[k])[i] : bf2f(((const unsigned short*)tab.src[k])[i]);
      base[tab.dstoff[k] + i] = v;
    }
  }
}

// ---- scan stage 1 ----
__global__ __launch_bounds__(256) void scan1_kernel(const int* __restrict__ deg,
                                                    int* __restrict__ excl,
                                                    int* __restrict__ bsum) {
  __shared__ int sm[256];
  int t = threadIdx.x, i = blockIdx.x * 256 + t;
  int v = (i < NPAD) ? deg[i] : 0;
  sm[t] = v;
  __syncthreads();
#pragma unroll
  for (int off = 1; off < 256; off <<= 1) {
    int add = (t >= off) ? sm[t - off] : 0;
    __syncthreads();
    sm[t] += add;
    __syncthreads();
  }
  if (i < NPAD) excl[i] = sm[t] - v;
  if (t == 255) bsum[blockIdx.x] = sm[255];
}

// ---- scan stages 2+3 fused ----
__global__ __launch_bounds__(256) void scan23_kernel(const int* __restrict__ excl,
                                                     const int* __restrict__ bsum,
                                                     int* __restrict__ rowstart) {
  __shared__ int sm[256];
  int t = threadIdx.x;
  int v = (t < SCAN_B) ? bsum[t] : 0;
  sm[t] = v;
  __syncthreads();
#pragma unroll
  for (int off = 1; off < 256; off <<= 1) {
    int add = (t >= off) ? sm[t - off] : 0;
    __syncthreads();
    sm[t] += add;
    __syncthreads();
  }
  int bpre = (blockIdx.x > 0) ? sm[blockIdx.x - 1] : 0;
  int i = blockIdx.x * 256 + t;
  if (i < NPAD) rowstart[i] = excl[i] + bpre;
  if (i == 0) rowstart[NPAD] = E_EDGES;
}

__global__ __launch_bounds__(256) void scatter_kernel(const int* __restrict__ dstA,
                                                      const int* __restrict__ pk,
                                                      const int* __restrict__ rowstart,
                                                      int* __restrict__ cnt,
                                                      int* __restrict__ eord) {
  int e = blockIdx.x * 256 + threadIdx.x;
  if (e >= E_EDGES) return;
  int d = dstA[e];
  int pos = rowstart[d] + atomicAdd(&cnt[d], 1);
  eord[pos] = pk[e];
}

// ====== GEMM: LDS-staged A (once per block), register-prefetched B ======
// Epilogue: acc -> LDS restage -> coalesced 16B vector stores.

// ---- xw[r,n,:] = h[n,:] @ W[r]; 4 waves = 4 (r,colpanel) of SAME 64 rows ----
__global__ __launch_bounds__(256) void gemm_xw_mfma(const unsigned short* __restrict__ hb,
                                                    const unsigned short* __restrict__ Wbt,
                                                    unsigned short* __restrict__ xw) {
  __shared__ unsigned short As[64][136];
  const int t = threadIdx.x;
  const int wave = t >> 6, lane = t & 63;
  const int row0 = blockIdx.x * 64;
  const int r = wave >> 1, colb = (wave & 1) * 64;
  const int lm = lane & 15, q = lane >> 4;
  const unsigned short* Bt = Wbt + (size_t)r * HID * HID;
  s16x8 bfr[4][4];
#pragma unroll
  for (int kc = 0; kc < 4; ++kc) {
    const int ko = kc * 32 + q * 8;
#pragma unroll
    for (int ct = 0; ct < 4; ++ct)
      bfr[kc][ct] = *(const s16x8*)(Bt + (size_t)(colb + ct * 16 + lm) * HID + ko);
  }
  const unsigned short* gsrc = hb + (size_t)row0 * HID;
#pragma unroll
  for (int j = 0; j < 4; ++j) {
    int idx = j * 256 + t;                      // 16B units, 1024 total
    *(s16x8*)&As[idx >> 4][(idx & 15) * 8] = *(const s16x8*)(gsrc + idx * 8);
  }
  __syncthreads();
  f32x4 acc[4][4];
#pragma unroll
  for (int a = 0; a < 4; ++a)
#pragma unroll
    for (int b = 0; b < 4; ++b) { f32x4 z = {0.f, 0.f, 0.f, 0.f}; acc[a][b] = z; }
#pragma unroll
  for (int kc = 0; kc < 4; ++kc) {
    const int ko = kc * 32 + q * 8;
#pragma unroll
    for (int rt = 0; rt < 4; ++rt) {
      s16x8 a = *(const s16x8*)&As[rt * 16 + lm][ko];
#pragma unroll
      for (int ct = 0; ct < 4; ++ct)
        acc[rt][ct] = __builtin_amdgcn_mfma_f32_16x16x32_bf16(a, bfr[kc][ct], acc[rt][ct], 0, 0, 0);
    }
  }
  __syncthreads();                              // As reads complete
  // two passes: restage r-plane in LDS, then coalesced copy-out
#pragma unroll
  for (int rr = 0; rr < 2; ++rr) {
    if (r == rr) {
#pragma unroll
      for (int rt = 0; rt < 4; ++rt)
#pragma unroll
        for (int i = 0; i < 4; ++i) {
          int rloc = rt * 16 + q * 4 + i;
#pragma unroll
          for (int ct = 0; ct < 4; ++ct)
            As[rloc][colb + ct * 16 + lm] = f2bf_bits(acc[rt][ct][i]);
        }
    }
    __syncthreads();
    unsigned short* dst = xw + ((size_t)rr * NPAD + row0) * HID;
#pragma unroll
    for (int j = 0; j < 4; ++j) {
      int idx = j * 256 + t;                    // 1024 16B units
      int rw = idx >> 4, cb8 = (idx & 15) * 8;
      if (row0 + rw < N_NODES)
        *(s16x8*)(dst + (size_t)rw * HID + cb8) = *(const s16x8*)&As[rw][cb8];
    }
    __syncthreads();
  }
}

// ---- out[n,o] = elu( agg[n,:] @ pW.T + bo ); 2 waves = 2 col panels ----
__global__ __launch_bounds__(128) void proj_mfma(const unsigned short* __restrict__ aggb,
                                                 const unsigned short* __restrict__ pWTb,
                                                 const float* __restrict__ bo,
                                                 unsigned short* __restrict__ hbout,
                                                 void* __restrict__ dout,
                                                 const int* __restrict__ flags) {
  __shared__ unsigned short As[64][136];
  const int t = threadIdx.x;
  const int wave = t >> 6, lane = t & 63;
  const int row0 = blockIdx.x * 64;
  const int colb = wave * 64;
  const int lm = lane & 15, q = lane >> 4;
  s16x8 bfr[4][4];
#pragma unroll
  for (int kc = 0; kc < 4; ++kc) {
    const int ko = kc * 32 + q * 8;
#pragma unroll
    for (int ct = 0; ct < 4; ++ct)
      bfr[kc][ct] = *(const s16x8*)(pWTb + (size_t)(colb + ct * 16 + lm) * HID + ko);
  }
  const unsigned short* gsrc = aggb + (size_t)row0 * HID;
#pragma unroll
  for (int j = 0; j < 8; ++j) {
    int idx = j * 128 + t;
    *(s16x8*)&As[idx >> 4][(idx & 15) * 8] = *(const s16x8*)(gsrc + idx * 8);
  }
  __syncthreads();
  f32x4 acc[4][4];
#pragma unroll
  for (int a = 0; a < 4; ++a)
#pragma unroll
    for (int b = 0; b < 4; ++b) { f32x4 z = {0.f, 0.f, 0.f, 0.f}; acc[a][b] = z; }
#pragma unroll
  for (int kc = 0; kc < 4; ++kc) {
    const int ko = kc * 32 + q * 8;
#pragma unroll
    for (int rt = 0; rt < 4; ++rt) {
      s16x8 a = *(const s16x8*)&As[rt * 16 + lm][ko];
#pragma unroll
      for (int ct = 0; ct < 4; ++ct)
        acc[rt][ct] = __builtin_amdgcn_mfma_f32_16x16x32_bf16(a, bfr[kc][ct], acc[rt][ct], 0, 0, 0);
    }
  }
  __syncthreads();                              // As reads complete
  const int f32final = (dout != nullptr) && flags[0];
  if (!f32final) {
    // bf16 destination: hb (layer 0) or bf16 d_out
    unsigned short* dstp = dout ? (unsigned short*)dout : hbout;
#pragma unroll
    for (int rt = 0; rt < 4; ++rt)
#pragma unroll
      for (int i = 0; i < 4; ++i) {
        int rloc = rt * 16 + q * 4 + i;
#pragma unroll
        for (int ct = 0; ct < 4; ++ct) {
          int o = colb + ct * 16 + lm;
          float v = acc[rt][ct][i] + bo[o];
          v = v > 0.f ? v : expm1f(v);          // ELU
          As[rloc][o] = f2bf_bits(v);
        }
      }
    __syncthreads();
#pragma unroll
    for (int j = 0; j < 8; ++j) {
      int idx = j * 128 + t;                    // 1024 16B units
      int rw = idx >> 4, cb8 = (idx & 15) * 8;
      if (row0 + rw < N_NODES)
        *(s16x8*)(dstp + (size_t)(row0 + rw) * HID + cb8) = *(const s16x8*)&As[rw][cb8];
    }
  } else {
    // f32 final output: two 32-row passes through a float view of As
    float* fdst = (float*)dout;
    float (*Fs)[132] = (float(*)[132])&As[0][0];   // 32*132*4 = 16896 B <= 17408
#pragma unroll
    for (int h = 0; h < 2; ++h) {
#pragma unroll
      for (int rt2 = 0; rt2 < 2; ++rt2) {
        const int rt = h * 2 + rt2;
#pragma unroll
        for (int i = 0; i < 4; ++i) {
          int rloc = rt2 * 16 + q * 4 + i;
#pragma unroll
          for (int ct = 0; ct < 4; ++ct) {
            int o = colb + ct * 16 + lm;
            float v = acc[rt][ct][i] + bo[o];
            v = v > 0.f ? v : expm1f(v);        // ELU
            Fs[rloc][o] = v;
          }
        }
      }
      __syncthreads();
#pragma unroll
      for (int j = 0; j < 8; ++j) {
        int idx = j * 128 + t;                  // 1024 float4 units (32 rows x 32)
        int rw = idx >> 5, cb4 = (idx & 31) * 4;
        if (row0 + h * 32 + rw < N_NODES)
          *(float4*)(fdst + (size_t)(row0 + h * 32 + rw) * HID + cb4) = *(const float4*)&Fs[rw][cb4];
      }
      __syncthreads();
    }
  }
}

// ---- WQ/WK fold -> split-bf16 table qkt[l][out16][128] ----
__global__ __launch_bounds__(256) void prep_wq_kernel(const unsigned short* __restrict__ Wbt,
                                                      const float* __restrict__ Qf,
                                                      const float* __restrict__ Kf,
                                                      unsigned short* __restrict__ qkt_hi,
                                                      unsigned short* __restrict__ qkt_lo) {
  int idx = blockIdx.x * 256 + threadIdx.x;   // (l,r,i)
  if (idx >= 2 * 2 * HID) return;
  int i = idx & 127, lr = idx >> 7, l = lr >> 1, r = (lr & 1);
  float aq[4] = {0.f, 0.f, 0.f, 0.f}, ak[4] = {0.f, 0.f, 0.f, 0.f};
  const unsigned short* Wb = Wbt + (size_t)lr * HID * HID;   // [o=j][i]
  const float* Qp = Qf + l * HID * HEADS;
  const float* Kp = Kf + l * HID * HEADS;
  for (int j = 0; j < HID; ++j) {
    float w = bf2f(Wb[j * HID + i]);
    float4 q4 = *(const float4*)(Qp + j * 4);
    float4 k4 = *(const float4*)(Kp + j * 4);
    aq[0] += w * q4.x; aq[1] += w * q4.y; aq[2] += w * q4.z; aq[3] += w * q4.w;
    ak[0] += w * k4.x; ak[1] += w * k4.y; ak[2] += w * k4.z; ak[3] += w * k4.w;
  }
  size_t base = (size_t)l * 16 * HID;
#pragma unroll
  for (int h = 0; h < 4; ++h) {
    unsigned short qh = f2bf_bits(aq[h]);
    unsigned short kh = f2bf_bits(ak[h]);
    float qres = aq[h] - bf2f(qh);
    float kres = ak[h] - bf2f(kh);
    qkt_hi[base + (size_t)(r * 4 + h) * HID + i] = qh;
    qkt_lo[base + (size_t)(r * 4 + h) * HID + i] = f2bf_bits(qres);
    qkt_hi[base + (size_t)(8 + r * 4 + h) * HID + i] = kh;
    qkt_lo[base + (size_t)(8 + r * 4 + h) * HID + i] = f2bf_bits(kres);
  }
}

// ---- qk via MFMA: [64 nodes]x[16 outs] per wave, split-bf16 B ----
__global__ __launch_bounds__(256) void qk_mfma_kernel(const unsigned short* __restrict__ hb,
                                                      const unsigned short* __restrict__ qkt_hi,
                                                      const unsigned short* __restrict__ qkt_lo,
                                                      float4* __restrict__ qi4,
                                                      float4* __restrict__ kj4) {
  __shared__ float st[4][16][68];
  const int wave = threadIdx.x >> 6, lane = threadIdx.x & 63;
  const int row0 = blockIdx.x * 256 + wave * 64;
  const int lm = lane & 15, q = lane >> 4;
  if (row0 < NPAD) {
    s16x8 bhi[4], blo[4], af[4][4];
#pragma unroll
    for (int kc = 0; kc < 4; ++kc) {
      const int ko = kc * 32 + q * 8;
      bhi[kc] = *(const s16x8*)(qkt_hi + (size_t)lm * HID + ko);
      blo[kc] = *(const s16x8*)(qkt_lo + (size_t)lm * HID + ko);
    }
#pragma unroll
    for (int kc = 0; kc < 4; ++kc) {
      const int ko = kc * 32 + q * 8;
#pragma unroll
      for (int rt = 0; rt < 4; ++rt)
        af[kc][rt] = *(const s16x8*)(hb + (size_t)(row0 + rt * 16 + lm) * HID + ko);
    }
    f32x4 acc[4];
#pragma unroll
    for (int a = 0; a < 4; ++a) { f32x4 z = {0.f, 0.f, 0.f, 0.f}; acc[a] = z; }
#pragma unroll
    for (int kc = 0; kc < 4; ++kc)
#pragma unroll
      for (int rt = 0; rt < 4; ++rt) {
        acc[rt] = __builtin_amdgcn_mfma_f32_16x16x32_bf16(af[kc][rt], bhi[kc], acc[rt], 0, 0, 0);
        acc[rt] = __builtin_amdgcn_mfma_f32_16x16x32_bf16(af[kc][rt], blo[kc], acc[rt], 0, 0, 0);
      }
#pragma unroll
    for (int rt = 0; rt < 4; ++rt)
      *(f32x4*)&st[wave][lm][rt * 16 + q * 4] = acc[rt];
  }
  __syncthreads();
  if (row0 < NPAD) {
    int n = row0 + lane;
    if (n < N_NODES) {
      float4 v;
      v.x = st[wave][0][lane]; v.y = st[wave][1][lane]; v.z = st[wave][2][lane]; v.w = st[wave][3][lane];
      qi4[n] = v;
      v.x = st[wave][4][lane]; v.y = st[wave][5][lane]; v.z = st[wave][6][lane]; v.w = st[wave][7][lane];
      qi4[NPAD + n] = v;
      v.x = st[wave][8][lane]; v.y = st[wave][9][lane]; v.z = st[wave][10][lane]; v.w = st[wave][11][lane];
      kj4[n] = v;
      v.x = st[wave][12][lane]; v.y = st[wave][13][lane]; v.z = st[wave][14][lane]; v.w = st[wave][15][lane];
      kj4[NPAD + n] = v;
    }
  }
}

// ---- quad kernel: 4 nodes/wave (deg<=16), 16 lanes/node, 8 ch/lane ----
// Each 16-lane group reads a full 256B xw row as one dwordx4/lane load;
// 4-level butterfly shared by 4 nodes. Arithmetic order identical to the
// 64-lane version -> bitwise-same output.
__global__ __launch_bounds__(256) void edge_quad_kernel(
    const int* __restrict__ rowstart, const int* __restrict__ eord,
    const float4* __restrict__ qi4, const float4* __restrict__ kj4,
    const unsigned short* __restrict__ xw, unsigned short* __restrict__ aggb,
    const int* __restrict__ nq, const int* __restrict__ bcnt) {
  __shared__ volatile float wls[16][4][17];   // [wave*4+g][head][edge] pad17: conflict-free reads
  const int t = threadIdx.x;
  const int wave = t >> 6, lane = t & 63;
  const int g = lane >> 4, li = lane & 15;
  const int idx = blockIdx.x * 16 + wave * 4 + g;
  const int cq = bcnt[0];
  const bool act = idx < cq;
  const int n = act ? nq[idx] : 0;
  const int start = rowstart[n];
  const int dg = act ? (rowstart[n + 1] - start) : 0;
  int p = 0;
  float w0 = 0.f, w1 = 0.f, w2 = 0.f, w3 = 0.f;
  if (li < dg) {
    p = eord[start + li];
    int s = p & 0xffff, r = p >> 16;
    float4 k4 = kj4[r ? (NPAD + s) : s];
    float4 q4 = r ? qi4[NPAD + n] : qi4[n];
    w0 = __expf(fminf(lrelu(q4.x + k4.x), 85.f));
    w1 = __expf(fminf(lrelu(q4.y + k4.y), 85.f));
    w2 = __expf(fminf(lrelu(q4.z + k4.z), 85.f));
    w3 = __expf(fminf(lrelu(q4.w + k4.w), 85.f));
  }
  const int wg = (wave << 2) | g;
  wls[wg][0][li] = w0; wls[wg][1][li] = w1;
  wls[wg][2][li] = w2; wls[wg][3][li] = w3;
  float s0 = w0, s1 = w1, s2 = w2, s3 = w3;
#pragma unroll
  for (int off = 8; off > 0; off >>= 1) {
    s0 += __shfl_xor(s0, off); s1 += __shfl_xor(s1, off);
    s2 += __shfl_xor(s2, off); s3 += __shfl_xor(s3, off);
  }
  const int hh = li >> 2;                       // 8 channels/lane span one head
  float ssel = hh == 0 ? s0 : hh == 1 ? s1 : hh == 2 ? s2 : s3;
  float a0 = 0.f, a1 = 0.f, a2 = 0.f, a3 = 0.f, a4 = 0.f, a5 = 0.f, a6 = 0.f, a7 = 0.f;
  volatile const float* wrh = &wls[wg][hh][0];
  const int co = li * 8;                        // ushort offset within row
  const int gbase = lane & 48;
#pragma unroll 1
  for (int e0 = 0; e0 < dg; e0 += 4) {
    int pe[4];
    uint4 v[4];
#pragma unroll
    for (int u = 0; u < 4; ++u) {
      int e = e0 + u;
      pe[u] = __shfl(p, gbase + (e < dg ? e : 0));
    }
#pragma unroll
    for (int u = 0; u < 4; ++u)
      v[u] = *(const uint4*)(xw + ((size_t)((pe[u] & 0xffff) + (pe[u] >> 16) * NPAD) << 7) + co);
#pragma unroll
    for (int u = 0; u < 4; ++u) {
      int e = e0 + u;
      float we = (e < dg) ? wrh[e] : 0.f;
      a0 = fmaf(lo_f(v[u].x), we, a0); a1 = fmaf(hi_f(v[u].x), we, a1);
      a2 = fmaf(lo_f(v[u].y), we, a2); a3 = fmaf(hi_f(v[u].y), we, a3);
      a4 = fmaf(lo_f(v[u].z), we, a4); a5 = fmaf(hi_f(v[u].z), we, a5);
      a6 = fmaf(lo_f(v[u].w), we, a6); a7 = fmaf(hi_f(v[u].w), we, a7);
    }
  }
  if (act) {
    float inv = 1.f / (ssel + 1e-16f);
    uint4 o;
    o.x = (unsigned)f2bf_bits(a0 * inv) | ((unsigned)f2bf_bits(a1 * inv) << 16);
    o.y = (unsigned)f2bf_bits(a2 * inv) | ((unsigned)f2bf_bits(a3 * inv) << 16);
    o.z = (unsigned)f2bf_bits(a4 * inv) | ((unsigned)f2bf_bits(a5 * inv) << 16);
    o.w = (unsigned)f2bf_bits(a6 * inv) | ((unsigned)f2bf_bits(a7 * inv) << 16);
    *(uint4*)(aggb + ((size_t)n << 7) + co) = o;
  }
}

// ---- big-node kernel: one wave per node (deg>16), list-driven ----
__global__ __launch_bounds__(256) void edge_big_kernel(
    const int* __restrict__ rowstart, const int* __restrict__ eord,
    const float4* __restrict__ qi4, const float4* __restrict__ kj4,
    const unsigned short* __restrict__ xw, unsigned short* __restrict__ aggb,
    const int* __restrict__ nw, const int* __restrict__ bcnt) {
  __shared__ volatile float wls[4][4][72];
  const int wave = threadIdx.x >> 6, lane = threadIdx.x & 63;
  const int idx = blockIdx.x * 4 + wave;
  const int cw = bcnt[1];
  if (idx >= cw) return;
  const int n = nw[idx];
  unsigned* outp = (unsigned*)(aggb + ((size_t)n << 7)) + lane;
  const int start = rowstart[n];
  const int deg = rowstart[n + 1] - start;
  const int hh = lane >> 4;
  const int ch2 = lane << 1;                    // ushort offset within a row
  float2 acc = {0.f, 0.f};
  float ssel;
  if (deg <= 64) {
    int p = 0;
    float w0 = 0.f, w1 = 0.f, w2 = 0.f, w3 = 0.f;
    if (lane < deg) {
      p = eord[start + lane];
      int s = p & 0xffff, r = p >> 16;
      float4 k4 = kj4[r ? (NPAD + s) : s];
      float4 q4 = r ? qi4[NPAD + n] : qi4[n];
      w0 = __expf(fminf(lrelu(q4.x + k4.x), 85.f));
      w1 = __expf(fminf(lrelu(q4.y + k4.y), 85.f));
      w2 = __expf(fminf(lrelu(q4.z + k4.z), 85.f));
      w3 = __expf(fminf(lrelu(q4.w + k4.w), 85.f));
    }
    float s0 = w0, s1 = w1, s2 = w2, s3 = w3;
#pragma unroll
    for (int off = 32; off > 0; off >>= 1) {
      s0 += __shfl_xor(s0, off); s1 += __shfl_xor(s1, off);
      s2 += __shfl_xor(s2, off); s3 += __shfl_xor(s3, off);
    }
    ssel = hh == 0 ? s0 : hh == 1 ? s1 : hh == 2 ? s2 : s3;
    wls[wave][0][lane] = w0;
    wls[wave][1][lane] = w1;
    wls[wave][2][lane] = w2;
    wls[wave][3][lane] = w3;
    volatile const float* wrh = &wls[wave][hh][0];   // broadcast reads
    const int degp = (deg + 15) & ~15;          // pad lanes: w=0, p=0 (row 0, L1-hot)
#pragma unroll 1
    for (int e = 0; e < degp; e += 16) {
      int pp[16];
      unsigned vv[16];
#pragma unroll
      for (int u = 0; u < 16; ++u)
        pp[u] = __builtin_amdgcn_readlane(p, e + u);
#pragma unroll
      for (int u = 0; u < 16; ++u)
        vv[u] = *(const unsigned*)(xw + ((size_t)((pp[u] & 0xffff) + (pp[u] >> 16) * NPAD) << 7) + ch2);
#pragma unroll
      for (int u = 0; u < 16; ++u) {
        float we = wrh[e + u];
        acc.x = fmaf(lo_f(vv[u]), we, acc.x);
        acc.y = fmaf(hi_f(vv[u]), we, acc.y);
      }
    }
  } else {
    // ---- generic fallback (deg > 64): wave-uniform serial, rare ----
    const float4 q0 = qi4[n], q1 = qi4[NPAD + n];
    float4 m = make_float4(-1e30f, -1e30f, -1e30f, -1e30f);
    for (int e = start; e < start + deg; ++e) {
      int pe = eord[e];
      int s = pe & 0xffff, r = pe >> 16;
      float4 k4 = kj4[(size_t)r * NPAD + s];
      float4 q4 = r ? q1 : q0;
      m.x = fmaxf(m.x, lrelu(q4.x + k4.x)); m.y = fmaxf(m.y, lrelu(q4.y + k4.y));
      m.z = fmaxf(m.z, lrelu(q4.z + k4.z)); m.w = fmaxf(m.w, lrelu(q4.w + k4.w));
    }
    float4 sv = make_float4(0.f, 0.f, 0.f, 0.f);
    for (int e = start; e < start + deg; ++e) {
      int pe = eord[e];
      int s = pe & 0xffff, r = pe >> 16;
      float4 k4 = kj4[(size_t)r * NPAD + s];
      float4 q4 = r ? q1 : q0;
      float w0 = __expf(lrelu(q4.x + k4.x) - m.x);
      float w1 = __expf(lrelu(q4.y + k4.y) - m.y);
      float w2 = __expf(lrelu(q4.z + k4.z) - m.z);
      float w3 = __expf(lrelu(q4.w + k4.w) - m.w);
      sv.x += w0; sv.y += w1; sv.z += w2; sv.w += w3;
      float we = hh == 0 ? w0 : hh == 1 ? w1 : hh == 2 ? w2 : w3;
      unsigned v = *(const unsigned*)(xw + (((size_t)r * NPAD + s) << 7) + ch2);
      acc.x = fmaf(lo_f(v), we, acc.x);
      acc.y = fmaf(hi_f(v), we, acc.y);
    }
    ssel = hh == 0 ? sv.x : hh == 1 ? sv.y : hh == 2 ? sv.z : sv.w;
  }
  float inv = 1.f / (ssel + 1e-16f);
  *outp = (unsigned)f2bf_bits(acc.x * inv) | ((unsigned)f2bf_bits(acc.y * inv) << 16);
}

// ---- both layers: pWTb2 + folded bias ----
__global__ __launch_bounds__(64) void prep_proj_kernel(const void* __restrict__ pW0,
                                                       const void* __restrict__ pW1,
                                                       const float* __restrict__ cbf,
                                                       const float* __restrict__ pbf,
                                                       unsigned short* __restrict__ pWTb2,
                                                       float* __restrict__ bo2,
                                                       const int* __restrict__ flags) {
  int o = blockIdx.x & 127, l = blockIdx.x >> 7, t = threadIdx.x;
  const void* pWraw = l ? pW1 : pW0;
  const float* cb = cbf + l * HID;
  const int f = flags[0];
  float part = 0.f;
#pragma unroll
  for (int i = t; i < HID; i += 64) {
    float w = f ? ((const float*)pWraw)[o * HID + i] : bf2f(((const unsigned short*)pWraw)[o * HID + i]);
    pWTb2[(size_t)l * HID * HID + o * HID + i] = f2bf_bits(w);
    part += cb[i] * w;
  }
#pragma unroll
  for (int off = 32; off > 0; off >>= 1) part += __shfl_xor(part, off);
  if (t == 0) bo2[l * HID + o] = pbf[l * HID + o] + part;
}

extern "C" void kernel_launch(void* const* d_in, const int* in_sizes, int n_in,
                              void* d_out, int out_size, void* d_ws, size_t ws_size,
                              hipStream_t stream) {
  const void* x     = d_in[0];
  const int*  eidx  = (const int*)d_in[1];
  const int*  etype = (const int*)d_in[2];
  const int iW[2] = {3, 9}, iQ[2] = {4, 10}, iK[2] = {5, 11}, icb[2] = {6, 12}, ipW[2] = {7, 13}, ipb[2] = {8, 14};

  float* ws = (float*)d_ws;
  size_t off = 0;
  int*   flags = (int*)(ws + off); off += 16;
  unsigned short* hb   = (unsigned short*)(ws + off); off += (size_t)NPAD * HID / 2;
  unsigned short* xw   = (unsigned short*)(ws + off); off += (size_t)NPAD * HID;       // [2][NPAD][128] bf16
  float* qi   = ws + off; off += (size_t)2 * NPAD * HEADS;
  float* kj   = ws + off; off += (size_t)2 * NPAD * HEADS;
  unsigned short* aggb = (unsigned short*)(ws + off); off += (size_t)NPAD * HID / 2;
  int* dstA = (int*)(ws + off); off += E_EDGES;
  int* pk   = (int*)(ws + off); off += E_EDGES;
  int* eord = (int*)(ws + off); off += E_EDGES;
  int* deg  = (int*)(ws + off); off += NPAD;        // deg|cnt|bcnt contiguous for one zero pass
  int* cnt  = (int*)(ws + off); off += NPAD;
  int* bcnt = (int*)(ws + off); off += 16;
  int* excl = (int*)(ws + off); off += NPAD;
  int* rowstart = (int*)(ws + off); off += NPAD + 16;
  int* bsum  = (int*)(ws + off); off += 256;
  int* nq   = (int*)(ws + off); off += NPAD;
  int* nwl  = (int*)(ws + off); off += NPAD;
  unsigned short* Wbt   = (unsigned short*)(ws + off); off += (size_t)2 * 2 * HID * HID / 2;
  unsigned short* pWTb2 = (unsigned short*)(ws + off); off += (size_t)2 * HID * HID / 2;
  unsigned short* qkt_hi = (unsigned short*)(ws + off); off += (size_t)2 * 16 * HID / 2;
  unsigned short* qkt_lo = (unsigned short*)(ws + off); off += (size_t)2 * 16 * HID / 2;
  float* Qf  = ws + off; off += 2 * HID * HEADS;
  float* Kf  = ws + off; off += 2 * HID * HEADS;
  float* cbf = ws + off; off += 2 * HID;
  float* pbf = ws + off; off += 2 * HID;
  float* bo2 = ws + off; off += 2 * HID;

  // ---- detect + zero (fused) + convert ----
  detect_zero_kernel<<<(2 * NPAD + 16 + 255) / 256, 256, 0, stream>>>((const unsigned short*)x, eidx, flags, deg, 2 * NPAD + 16);
  cvt_idx_hist_kernel<<<(E_EDGES + 255) / 256, 256, 0, stream>>>(eidx, etype, dstA, pk, deg, flags);
  bucket_kernel<<<(N_NODES + 255) / 256, 256, 0, stream>>>(deg, bcnt, nq, nwl);
  cvt_xb_kernel<<<(N_NODES * HID / 8 + 255) / 256, 256, 0, stream>>>(x, hb, N_NODES * HID / 8, flags);
  cvt_wt_kernel<<<(2 * 2 * HID * HID + 255) / 256, 256, 0, stream>>>(d_in[iW[0]], d_in[iW[1]], Wbt, flags);
  {
    P8 tab;
    float* base = ws;
    for (int l = 0; l < 2; ++l) {
      tab.src[l * 4 + 0] = d_in[iQ[l]];  tab.dstoff[l * 4 + 0] = (int)(Qf - base) + l * HID * HEADS;  tab.n[l * 4 + 0] = HID * HEADS;
      tab.src[l * 4 + 1] = d_in[iK[l]];  tab.dstoff[l * 4 + 1] = (int)(Kf - base) + l * HID * HEADS;  tab.n[l * 4 + 1] = HID * HEADS;
      tab.src[l * 4 + 2] = d_in[icb[l]]; tab.dstoff[l * 4 + 2] = (int)(cbf - base) + l * HID;         tab.n[l * 4 + 2] = HID;
      tab.src[l * 4 + 3] = d_in[ipb[l]]; tab.dstoff[l * 4 + 3] = (int)(pbf - base) + l * HID;         tab.n[l * 4 + 3] = HID;
    }
    cvt_params_kernel<<<2, 256, 0, stream>>>(tab, base, flags);
  }

  // ---- counting sort by dst ----
  scan1_kernel<<<SCAN_B, 256, 0, stream>>>(deg, excl, bsum);
  scan23_kernel<<<SCAN_B, 256, 0, stream>>>(excl, bsum, rowstart);
  scatter_kernel<<<(E_EDGES + 255) / 256, 256, 0, stream>>>(dstA, pk, rowstart, cnt, eord);

  // ---- folded params ----
  prep_wq_kernel<<<2, 256, 0, stream>>>(Wbt, Qf, Kf, qkt_hi, qkt_lo);
  prep_proj_kernel<<<2 * HID, 64, 0, stream>>>(d_in[ipW[0]], d_in[ipW[1]], cbf, pbf, pWTb2, bo2, flags);

  const int RB = NPAD / 64;   // 782 row-blocks
  const int QB = (NPAD + 255) / 256;
  for (int l = 0; l < 2; ++l) {
    gemm_xw_mfma<<<RB, 256, 0, stream>>>(hb, Wbt + (size_t)l * 2 * HID * HID, xw);
    qk_mfma_kernel<<<QB, 256, 0, stream>>>(hb, qkt_hi + (size_t)l * 16 * HID, qkt_lo + (size_t)l * 16 * HID,
                                           (float4*)qi, (float4*)kj);
    edge_quad_kernel<<<(N_NODES + 15) / 16, 256, 0, stream>>>(rowstart, eord, (const float4*)qi, (const float4*)kj,
                                                              xw, aggb, nq, bcnt);
    edge_big_kernel<<<(N_NODES + 3) / 4, 256, 0, stream>>>(rowstart, eord, (const float4*)qi, (const float4*)kj,
                                                           xw, aggb, nwl, bcnt);
    proj_mfma<<<RB, 128, 0, stream>>>(aggb, pWTb2 + (size_t)l * HID * HID, bo2 + l * HID, hb,
                                      (l == 1) ? d_out : nullptr, flags);
  }
}

// Round 4
// 374.345 us; speedup vs baseline: 2.3303x; 2.3303x over previous
//
#include <hip/hip_runtime.h>
#include <hip/hip_bf16.h>

typedef __hip_bfloat16 bf16;
typedef short s16x8 __attribute__((ext_vector_type(8)));
typedef float f32x4 __attribute__((ext_vector_type(4)));

#define N_NODES 50000
#define NPAD    50048          // multiple of 64
#define E_EDGES 600000
#define HID     128
#define HEADS   4
#define SCAN_B  196            // ceil(NPAD/256)

// ---- float -> bf16 bits (RNE), finite inputs only ----
__device__ __forceinline__ unsigned short f2bf_bits(float f) {
  unsigned u = __float_as_uint(f);
  u += 0x7fffu + ((u >> 16) & 1u);
  return (unsigned short)(u >> 16);
}
__device__ __forceinline__ float bf2f(unsigned short b) {
  return __uint_as_float(((unsigned)b) << 16);
}
// packed-dword bf16 pair -> floats (1 op each)
__device__ __forceinline__ float lo_f(unsigned v) { return __uint_as_float(v << 16); }
__device__ __forceinline__ float hi_f(unsigned v) { return __uint_as_float(v & 0xffff0000u); }

// lrelu(x) = max(x, 0.2x) for slope in (0,1): 2 VALU ops
__device__ __forceinline__ float lrelu(float v) { return fmaxf(v, 0.2f * v); }

// ---- runtime dtype detection + zero (fused: one dispatch) ----
__global__ __launch_bounds__(256) void detect_zero_kernel(const unsigned short* __restrict__ xb,
                                                          const int* __restrict__ ei,
                                                          int* __restrict__ flags,
                                                          int* __restrict__ zp, int nz) {
  int t = threadIdx.x;
  int i = blockIdx.x * 256 + t;
  if (i < nz) zp[i] = 0;
  if (blockIdx.x == 0) {
    __shared__ int cnt[2];
    if (t < 2) cnt[t] = 0;
    __syncthreads();
    unsigned short v = xb[2 * t];
    int ex = (v >> 7) & 0xFF;
    if (ex < 119 || ex > 135) atomicAdd(&cnt[0], 1);
    if (ei[2 * t + 1] != 0) atomicAdd(&cnt[1], 1);
    __syncthreads();
    if (t == 0) {
      flags[0] = (cnt[0] > 64) ? 1 : 0;
      flags[1] = (cnt[1] == 0) ? 1 : 0;
    }
  }
}

// ---- index conversion + degree histogram ----
__global__ __launch_bounds__(256) void cvt_idx_hist_kernel(const int* __restrict__ eidx,
                                                           const int* __restrict__ etype,
                                                           int* __restrict__ dstA, int* __restrict__ pk,
                                                           int* __restrict__ deg,
                                                           const int* __restrict__ flags) {
  int e = blockIdx.x * 256 + threadIdx.x;
  if (e >= E_EDGES) return;
  int s, d, r;
  if (flags[1]) {
    const long long* e64 = (const long long*)eidx;
    const long long* t64 = (const long long*)etype;
    s = (int)e64[e]; d = (int)e64[E_EDGES + e]; r = (int)t64[e];
  } else {
    s = eidx[e]; d = eidx[E_EDGES + e]; r = etype[e];
  }
  dstA[e] = d;
  pk[e] = s | (r << 16);
  atomicAdd(&deg[d], 1);
}

// ---- degree-class bucketing: deg<=16 -> nq (quad), else nw ----
// Wave-aggregated atomics: ballot + 1 atomicAdd per wave per bucket
// (50000 same-address atomic-returns was 512us of pure serialization).
__global__ __launch_bounds__(256) void bucket_kernel(const int* __restrict__ deg,
                                                     int* __restrict__ bcnt,
                                                     int* __restrict__ nq,
                                                     int* __restrict__ nw) {
  int n = blockIdx.x * 256 + threadIdx.x;
  int lane = threadIdx.x & 63;
  bool valid = n < N_NODES;
  int d = valid ? deg[n] : 0;
  bool isq = valid && (d <= 16);
  bool isw = valid && (d > 16);
  unsigned long long mq = __ballot(isq);
  unsigned long long mw = __ballot(isw);
  unsigned long long lower = (lane == 63) ? 0x7fffffffffffffffull : ((1ull << lane) - 1ull);
  int baseq = 0, basew = 0;
  int lq = (int)__ffsll((unsigned long long)mq) - 1;
  int lw = (int)__ffsll((unsigned long long)mw) - 1;
  if (mq && lane == lq) baseq = atomicAdd(&bcnt[0], (int)__popcll(mq));
  if (mw && lane == lw) basew = atomicAdd(&bcnt[1], (int)__popcll(mw));
  if (mq) baseq = __shfl(baseq, lq);
  if (mw) basew = __shfl(basew, lw);
  if (isq) nq[baseq + (int)__popcll(mq & lower)] = n;
  if (isw) nw[basew + (int)__popcll(mw & lower)] = n;
}

// ---- float-tensor -> bf16 bits, 8 elems/thread (vectorized) ----
__global__ __launch_bounds__(256) void cvt_xb_kernel(const void* __restrict__ src,
                                                     unsigned short* __restrict__ dst, int n8,
                                                     const int* __restrict__ flags) {
  int i = blockIdx.x * 256 + threadIdx.x;
  if (i >= n8) return;
  if (flags[0]) {
    const float4* s4 = (const float4*)src;
    float4 a = s4[2 * i], b = s4[2 * i + 1];
    s16x8 o;
    o[0] = (short)f2bf_bits(a.x); o[1] = (short)f2bf_bits(a.y);
    o[2] = (short)f2bf_bits(a.z); o[3] = (short)f2bf_bits(a.w);
    o[4] = (short)f2bf_bits(b.x); o[5] = (short)f2bf_bits(b.y);
    o[6] = (short)f2bf_bits(b.z); o[7] = (short)f2bf_bits(b.w);
    *(s16x8*)(dst + (size_t)i * 8) = o;
  } else {
    *(s16x8*)(dst + (size_t)i * 8) = ((const s16x8*)src)[i];
  }
}

// ---- W (both layers) -> bf16 N-major [l][r][o][i] ----
__global__ __launch_bounds__(256) void cvt_wt_kernel(const void* __restrict__ src0,
                                                     const void* __restrict__ src1,
                                                     unsigned short* __restrict__ dst,
                                                     const int* __restrict__ flags) {
  int idx = blockIdx.x * 256 + threadIdx.x;
  if (idx >= 2 * 2 * HID * HID) return;
  int l = idx >> 15, rem = idx & 32767;
  int r = rem >> 14, i = (rem >> 7) & 127, o = rem & 127;
  const void* src = l ? src1 : src0;
  unsigned short b;
  if (flags[0]) b = f2bf_bits(((const float*)src)[rem]);
  else          b = ((const unsigned short*)src)[rem];
  dst[(size_t)l * 2 * HID * HID + ((size_t)r * HID + o) * HID + i] = b;
}

// ---- small params -> fp32 block ----
struct P8 { const void* src[8]; int dstoff[8]; int n[8]; };
__global__ __launch_bounds__(256) void cvt_params_kernel(P8 tab, float* __restrict__ base,
                                                         const int* __restrict__ flags) {
  const int f = flags[0];
  for (int k = 0; k < 8; ++k) {
    int n = tab.n[k];
    for (int i = blockIdx.x * 256 + threadIdx.x; i < n; i += gridDim.x * 256) {
      float v = f ? ((const float*)tab.src[k])[i] : bf2f(((const unsigned short*)tab.src[k])[i]);
      base[tab.dstoff[k] + i] = v;
    }
  }
}

// ---- scan stage 1 ----
__global__ __launch_bounds__(256) void scan1_kernel(const int* __restrict__ deg,
                                                    int* __restrict__ excl,
                                                    int* __restrict__ bsum) {
  __shared__ int sm[256];
  int t = threadIdx.x, i = blockIdx.x * 256 + t;
  int v = (i < NPAD) ? deg[i] : 0;
  sm[t] = v;
  __syncthreads();
#pragma unroll
  for (int off = 1; off < 256; off <<= 1) {
    int add = (t >= off) ? sm[t - off] : 0;
    __syncthreads();
    sm[t] += add;
    __syncthreads();
  }
  if (i < NPAD) excl[i] = sm[t] - v;
  if (t == 255) bsum[blockIdx.x] = sm[255];
}

// ---- scan stages 2+3 fused ----
__global__ __launch_bounds__(256) void scan23_kernel(const int* __restrict__ excl,
                                                     const int* __restrict__ bsum,
                                                     int* __restrict__ rowstart) {
  __shared__ int sm[256];
  int t = threadIdx.x;
  int v = (t < SCAN_B) ? bsum[t] : 0;
  sm[t] = v;
  __syncthreads();
#pragma unroll
  for (int off = 1; off < 256; off <<= 1) {
    int add = (t >= off) ? sm[t - off] : 0;
    __syncthreads();
    sm[t] += add;
    __syncthreads();
  }
  int bpre = (blockIdx.x > 0) ? sm[blockIdx.x - 1] : 0;
  int i = blockIdx.x * 256 + t;
  if (i < NPAD) rowstart[i] = excl[i] + bpre;
  if (i == 0) rowstart[NPAD] = E_EDGES;
}

__global__ __launch_bounds__(256) void scatter_kernel(const int* __restrict__ dstA,
                                                      const int* __restrict__ pk,
                                                      const int* __restrict__ rowstart,
                                                      int* __restrict__ cnt,
                                                      int* __restrict__ eord) {
  int e = blockIdx.x * 256 + threadIdx.x;
  if (e >= E_EDGES) return;
  int d = dstA[e];
  int pos = rowstart[d] + atomicAdd(&cnt[d], 1);
  eord[pos] = pk[e];
}

// ====== GEMM: LDS-staged A (once per block), register-prefetched B ======
// Epilogue: acc -> LDS restage -> coalesced 16B vector stores.

// ---- xw[r,n,:] = h[n,:] @ W[r]; 4 waves = 4 (r,colpanel) of SAME 64 rows ----
__global__ __launch_bounds__(256) void gemm_xw_mfma(const unsigned short* __restrict__ hb,
                                                    const unsigned short* __restrict__ Wbt,
                                                    unsigned short* __restrict__ xw) {
  __shared__ unsigned short As[64][136];
  const int t = threadIdx.x;
  const int wave = t >> 6, lane = t & 63;
  const int row0 = blockIdx.x * 64;
  const int r = wave >> 1, colb = (wave & 1) * 64;
  const int lm = lane & 15, q = lane >> 4;
  const unsigned short* Bt = Wbt + (size_t)r * HID * HID;
  s16x8 bfr[4][4];
#pragma unroll
  for (int kc = 0; kc < 4; ++kc) {
    const int ko = kc * 32 + q * 8;
#pragma unroll
    for (int ct = 0; ct < 4; ++ct)
      bfr[kc][ct] = *(const s16x8*)(Bt + (size_t)(colb + ct * 16 + lm) * HID + ko);
  }
  const unsigned short* gsrc = hb + (size_t)row0 * HID;
#pragma unroll
  for (int j = 0; j < 4; ++j) {
    int idx = j * 256 + t;                      // 16B units, 1024 total
    *(s16x8*)&As[idx >> 4][(idx & 15) * 8] = *(const s16x8*)(gsrc + idx * 8);
  }
  __syncthreads();
  f32x4 acc[4][4];
#pragma unroll
  for (int a = 0; a < 4; ++a)
#pragma unroll
    for (int b = 0; b < 4; ++b) { f32x4 z = {0.f, 0.f, 0.f, 0.f}; acc[a][b] = z; }
#pragma unroll
  for (int kc = 0; kc < 4; ++kc) {
    const int ko = kc * 32 + q * 8;
#pragma unroll
    for (int rt = 0; rt < 4; ++rt) {
      s16x8 a = *(const s16x8*)&As[rt * 16 + lm][ko];
#pragma unroll
      for (int ct = 0; ct < 4; ++ct)
        acc[rt][ct] = __builtin_amdgcn_mfma_f32_16x16x32_bf16(a, bfr[kc][ct], acc[rt][ct], 0, 0, 0);
    }
  }
  __syncthreads();                              // As reads complete
  // two passes: restage r-plane in LDS, then coalesced copy-out
#pragma unroll
  for (int rr = 0; rr < 2; ++rr) {
    if (r == rr) {
#pragma unroll
      for (int rt = 0; rt < 4; ++rt)
#pragma unroll
        for (int i = 0; i < 4; ++i) {
          int rloc = rt * 16 + q * 4 + i;
#pragma unroll
          for (int ct = 0; ct < 4; ++ct)
            As[rloc][colb + ct * 16 + lm] = f2bf_bits(acc[rt][ct][i]);
        }
    }
    __syncthreads();
    unsigned short* dst = xw + ((size_t)rr * NPAD + row0) * HID;
#pragma unroll
    for (int j = 0; j < 4; ++j) {
      int idx = j * 256 + t;                    // 1024 16B units
      int rw = idx >> 4, cb8 = (idx & 15) * 8;
      if (row0 + rw < N_NODES)
        *(s16x8*)(dst + (size_t)rw * HID + cb8) = *(const s16x8*)&As[rw][cb8];
    }
    __syncthreads();
  }
}

// ---- out[n,o] = elu( agg[n,:] @ pW.T + bo ); 2 waves = 2 col panels ----
__global__ __launch_bounds__(128) void proj_mfma(const unsigned short* __restrict__ aggb,
                                                 const unsigned short* __restrict__ pWTb,
                                                 const float* __restrict__ bo,
                                                 unsigned short* __restrict__ hbout,
                                                 void* __restrict__ dout,
                                                 const int* __restrict__ flags) {
  __shared__ unsigned short As[64][136];
  const int t = threadIdx.x;
  const int wave = t >> 6, lane = t & 63;
  const int row0 = blockIdx.x * 64;
  const int colb = wave * 64;
  const int lm = lane & 15, q = lane >> 4;
  s16x8 bfr[4][4];
#pragma unroll
  for (int kc = 0; kc < 4; ++kc) {
    const int ko = kc * 32 + q * 8;
#pragma unroll
    for (int ct = 0; ct < 4; ++ct)
      bfr[kc][ct] = *(const s16x8*)(pWTb + (size_t)(colb + ct * 16 + lm) * HID + ko);
  }
  const unsigned short* gsrc = aggb + (size_t)row0 * HID;
#pragma unroll
  for (int j = 0; j < 8; ++j) {
    int idx = j * 128 + t;
    *(s16x8*)&As[idx >> 4][(idx & 15) * 8] = *(const s16x8*)(gsrc + idx * 8);
  }
  __syncthreads();
  f32x4 acc[4][4];
#pragma unroll
  for (int a = 0; a < 4; ++a)
#pragma unroll
    for (int b = 0; b < 4; ++b) { f32x4 z = {0.f, 0.f, 0.f, 0.f}; acc[a][b] = z; }
#pragma unroll
  for (int kc = 0; kc < 4; ++kc) {
    const int ko = kc * 32 + q * 8;
#pragma unroll
    for (int rt = 0; rt < 4; ++rt) {
      s16x8 a = *(const s16x8*)&As[rt * 16 + lm][ko];
#pragma unroll
      for (int ct = 0; ct < 4; ++ct)
        acc[rt][ct] = __builtin_amdgcn_mfma_f32_16x16x32_bf16(a, bfr[kc][ct], acc[rt][ct], 0, 0, 0);
    }
  }
  __syncthreads();                              // As reads complete
  const int f32final = (dout != nullptr) && flags[0];
  if (!f32final) {
    // bf16 destination: hb (layer 0) or bf16 d_out
    unsigned short* dstp = dout ? (unsigned short*)dout : hbout;
#pragma unroll
    for (int rt = 0; rt < 4; ++rt)
#pragma unroll
      for (int i = 0; i < 4; ++i) {
        int rloc = rt * 16 + q * 4 + i;
#pragma unroll
        for (int ct = 0; ct < 4; ++ct) {
          int o = colb + ct * 16 + lm;
          float v = acc[rt][ct][i] + bo[o];
          v = v > 0.f ? v : expm1f(v);          // ELU
          As[rloc][o] = f2bf_bits(v);
        }
      }
    __syncthreads();
#pragma unroll
    for (int j = 0; j < 8; ++j) {
      int idx = j * 128 + t;                    // 1024 16B units
      int rw = idx >> 4, cb8 = (idx & 15) * 8;
      if (row0 + rw < N_NODES)
        *(s16x8*)(dstp + (size_t)(row0 + rw) * HID + cb8) = *(const s16x8*)&As[rw][cb8];
    }
  } else {
    // f32 final output: two 32-row passes through a float view of As
    float* fdst = (float*)dout;
    float (*Fs)[132] = (float(*)[132])&As[0][0];   // 32*132*4 = 16896 B <= 17408
#pragma unroll
    for (int h = 0; h < 2; ++h) {
#pragma unroll
      for (int rt2 = 0; rt2 < 2; ++rt2) {
        const int rt = h * 2 + rt2;
#pragma unroll
        for (int i = 0; i < 4; ++i) {
          int rloc = rt2 * 16 + q * 4 + i;
#pragma unroll
          for (int ct = 0; ct < 4; ++ct) {
            int o = colb + ct * 16 + lm;
            float v = acc[rt][ct][i] + bo[o];
            v = v > 0.f ? v : expm1f(v);        // ELU
            Fs[rloc][o] = v;
          }
        }
      }
      __syncthreads();
#pragma unroll
      for (int j = 0; j < 8; ++j) {
        int idx = j * 128 + t;                  // 1024 float4 units (32 rows x 32)
        int rw = idx >> 5, cb4 = (idx & 31) * 4;
        if (row0 + h * 32 + rw < N_NODES)
          *(float4*)(fdst + (size_t)(row0 + h * 32 + rw) * HID + cb4) = *(const float4*)&Fs[rw][cb4];
      }
      __syncthreads();
    }
  }
}

// ---- WQ/WK fold -> split-bf16 table qkt[l][out16][128] ----
__global__ __launch_bounds__(256) void prep_wq_kernel(const unsigned short* __restrict__ Wbt,
                                                      const float* __restrict__ Qf,
                                                      const float* __restrict__ Kf,
                                                      unsigned short* __restrict__ qkt_hi,
                                                      unsigned short* __restrict__ qkt_lo) {
  int idx = blockIdx.x * 256 + threadIdx.x;   // (l,r,i)
  if (idx >= 2 * 2 * HID) return;
  int i = idx & 127, lr = idx >> 7, l = lr >> 1, r = (lr & 1);
  float aq[4] = {0.f, 0.f, 0.f, 0.f}, ak[4] = {0.f, 0.f, 0.f, 0.f};
  const unsigned short* Wb = Wbt + (size_t)lr * HID * HID;   // [o=j][i]
  const float* Qp = Qf + l * HID * HEADS;
  const float* Kp = Kf + l * HID * HEADS;
  for (int j = 0; j < HID; ++j) {
    float w = bf2f(Wb[j * HID + i]);
    float4 q4 = *(const float4*)(Qp + j * 4);
    float4 k4 = *(const float4*)(Kp + j * 4);
    aq[0] += w * q4.x; aq[1] += w * q4.y; aq[2] += w * q4.z; aq[3] += w * q4.w;
    ak[0] += w * k4.x; ak[1] += w * k4.y; ak[2] += w * k4.z; ak[3] += w * k4.w;
  }
  size_t base = (size_t)l * 16 * HID;
#pragma unroll
  for (int h = 0; h < 4; ++h) {
    unsigned short qh = f2bf_bits(aq[h]);
    unsigned short kh = f2bf_bits(ak[h]);
    float qres = aq[h] - bf2f(qh);
    float kres = ak[h] - bf2f(kh);
    qkt_hi[base + (size_t)(r * 4 + h) * HID + i] = qh;
    qkt_lo[base + (size_t)(r * 4 + h) * HID + i] = f2bf_bits(qres);
    qkt_hi[base + (size_t)(8 + r * 4 + h) * HID + i] = kh;
    qkt_lo[base + (size_t)(8 + r * 4 + h) * HID + i] = f2bf_bits(kres);
  }
}

// ---- qk via MFMA: [64 nodes]x[16 outs] per wave, split-bf16 B ----
__global__ __launch_bounds__(256) void qk_mfma_kernel(const unsigned short* __restrict__ hb,
                                                      const unsigned short* __restrict__ qkt_hi,
                                                      const unsigned short* __restrict__ qkt_lo,
                                                      float4* __restrict__ qi4,
                                                      float4* __restrict__ kj4) {
  __shared__ float st[4][16][68];
  const int wave = threadIdx.x >> 6, lane = threadIdx.x & 63;
  const int row0 = blockIdx.x * 256 + wave * 64;
  const int lm = lane & 15, q = lane >> 4;
  if (row0 < NPAD) {
    s16x8 bhi[4], blo[4], af[4][4];
#pragma unroll
    for (int kc = 0; kc < 4; ++kc) {
      const int ko = kc * 32 + q * 8;
      bhi[kc] = *(const s16x8*)(qkt_hi + (size_t)lm * HID + ko);
      blo[kc] = *(const s16x8*)(qkt_lo + (size_t)lm * HID + ko);
    }
#pragma unroll
    for (int kc = 0; kc < 4; ++kc) {
      const int ko = kc * 32 + q * 8;
#pragma unroll
      for (int rt = 0; rt < 4; ++rt)
        af[kc][rt] = *(const s16x8*)(hb + (size_t)(row0 + rt * 16 + lm) * HID + ko);
    }
    f32x4 acc[4];
#pragma unroll
    for (int a = 0; a < 4; ++a) { f32x4 z = {0.f, 0.f, 0.f, 0.f}; acc[a] = z; }
#pragma unroll
    for (int kc = 0; kc < 4; ++kc)
#pragma unroll
      for (int rt = 0; rt < 4; ++rt) {
        acc[rt] = __builtin_amdgcn_mfma_f32_16x16x32_bf16(af[kc][rt], bhi[kc], acc[rt], 0, 0, 0);
        acc[rt] = __builtin_amdgcn_mfma_f32_16x16x32_bf16(af[kc][rt], blo[kc], acc[rt], 0, 0, 0);
      }
#pragma unroll
    for (int rt = 0; rt < 4; ++rt)
      *(f32x4*)&st[wave][lm][rt * 16 + q * 4] = acc[rt];
  }
  __syncthreads();
  if (row0 < NPAD) {
    int n = row0 + lane;
    if (n < N_NODES) {
      float4 v;
      v.x = st[wave][0][lane]; v.y = st[wave][1][lane]; v.z = st[wave][2][lane]; v.w = st[wave][3][lane];
      qi4[n] = v;
      v.x = st[wave][4][lane]; v.y = st[wave][5][lane]; v.z = st[wave][6][lane]; v.w = st[wave][7][lane];
      qi4[NPAD + n] = v;
      v.x = st[wave][8][lane]; v.y = st[wave][9][lane]; v.z = st[wave][10][lane]; v.w = st[wave][11][lane];
      kj4[n] = v;
      v.x = st[wave][12][lane]; v.y = st[wave][13][lane]; v.z = st[wave][14][lane]; v.w = st[wave][15][lane];
      kj4[NPAD + n] = v;
    }
  }
}

// ---- quad kernel: 4 nodes/wave (deg<=16), 16 lanes/node, 8 ch/lane ----
__global__ __launch_bounds__(256) void edge_quad_kernel(
    const int* __restrict__ rowstart, const int* __restrict__ eord,
    const float4* __restrict__ qi4, const float4* __restrict__ kj4,
    const unsigned short* __restrict__ xw, unsigned short* __restrict__ aggb,
    const int* __restrict__ nq, const int* __restrict__ bcnt) {
  __shared__ volatile float wls[16][4][17];   // [wave*4+g][head][edge] pad17: conflict-free reads
  const int t = threadIdx.x;
  const int wave = t >> 6, lane = t & 63;
  const int g = lane >> 4, li = lane & 15;
  const int idx = blockIdx.x * 16 + wave * 4 + g;
  const int cq = bcnt[0];
  const bool act = idx < cq;
  const int n = act ? nq[idx] : 0;
  const int start = rowstart[n];
  const int dg = act ? (rowstart[n + 1] - start) : 0;
  int p = 0;
  float w0 = 0.f, w1 = 0.f, w2 = 0.f, w3 = 0.f;
  if (li < dg) {
    p = eord[start + li];
    int s = p & 0xffff, r = p >> 16;
    float4 k4 = kj4[r ? (NPAD + s) : s];
    float4 q4 = r ? qi4[NPAD + n] : qi4[n];
    w0 = __expf(fminf(lrelu(q4.x + k4.x), 85.f));
    w1 = __expf(fminf(lrelu(q4.y + k4.y), 85.f));
    w2 = __expf(fminf(lrelu(q4.z + k4.z), 85.f));
    w3 = __expf(fminf(lrelu(q4.w + k4.w), 85.f));
  }
  const int wg = (wave << 2) | g;
  wls[wg][0][li] = w0; wls[wg][1][li] = w1;
  wls[wg][2][li] = w2; wls[wg][3][li] = w3;
  float s0 = w0, s1 = w1, s2 = w2, s3 = w3;
#pragma unroll
  for (int off = 8; off > 0; off >>= 1) {
    s0 += __shfl_xor(s0, off); s1 += __shfl_xor(s1, off);
    s2 += __shfl_xor(s2, off); s3 += __shfl_xor(s3, off);
  }
  const int hh = li >> 2;                       // 8 channels/lane span one head
  float ssel = hh == 0 ? s0 : hh == 1 ? s1 : hh == 2 ? s2 : s3;
  float a0 = 0.f, a1 = 0.f, a2 = 0.f, a3 = 0.f, a4 = 0.f, a5 = 0.f, a6 = 0.f, a7 = 0.f;
  volatile const float* wrh = &wls[wg][hh][0];
  const int co = li * 8;                        // ushort offset within row
  const int gbase = lane & 48;
#pragma unroll 1
  for (int e0 = 0; e0 < dg; e0 += 4) {
    int pe[4];
    uint4 v[4];
#pragma unroll
    for (int u = 0; u < 4; ++u) {
      int e = e0 + u;
      pe[u] = __shfl(p, gbase + (e < dg ? e : 0));
    }
#pragma unroll
    for (int u = 0; u < 4; ++u)
      v[u] = *(const uint4*)(xw + ((size_t)((pe[u] & 0xffff) + (pe[u] >> 16) * NPAD) << 7) + co);
#pragma unroll
    for (int u = 0; u < 4; ++u) {
      int e = e0 + u;
      float we = (e < dg) ? wrh[e] : 0.f;
      a0 = fmaf(lo_f(v[u].x), we, a0); a1 = fmaf(hi_f(v[u].x), we, a1);
      a2 = fmaf(lo_f(v[u].y), we, a2); a3 = fmaf(hi_f(v[u].y), we, a3);
      a4 = fmaf(lo_f(v[u].z), we, a4); a5 = fmaf(hi_f(v[u].z), we, a5);
      a6 = fmaf(lo_f(v[u].w), we, a6); a7 = fmaf(hi_f(v[u].w), we, a7);
    }
  }
  if (act) {
    float inv = 1.f / (ssel + 1e-16f);
    uint4 o;
    o.x = (unsigned)f2bf_bits(a0 * inv) | ((unsigned)f2bf_bits(a1 * inv) << 16);
    o.y = (unsigned)f2bf_bits(a2 * inv) | ((unsigned)f2bf_bits(a3 * inv) << 16);
    o.z = (unsigned)f2bf_bits(a4 * inv) | ((unsigned)f2bf_bits(a5 * inv) << 16);
    o.w = (unsigned)f2bf_bits(a6 * inv) | ((unsigned)f2bf_bits(a7 * inv) << 16);
    *(uint4*)(aggb + ((size_t)n << 7) + co) = o;
  }
}

// ---- big-node kernel: one wave per node (deg>16), list-driven ----
__global__ __launch_bounds__(256) void edge_big_kernel(
    const int* __restrict__ rowstart, const int* __restrict__ eord,
    const float4* __restrict__ qi4, const float4* __restrict__ kj4,
    const unsigned short* __restrict__ xw, unsigned short* __restrict__ aggb,
    const int* __restrict__ nw, const int* __restrict__ bcnt) {
  __shared__ volatile float wls[4][4][72];
  const int wave = threadIdx.x >> 6, lane = threadIdx.x & 63;
  const int idx = blockIdx.x * 4 + wave;
  const int cw = bcnt[1];
  if (idx >= cw) return;
  const int n = nw[idx];
  unsigned* outp = (unsigned*)(aggb + ((size_t)n << 7)) + lane;
  const int start = rowstart[n];
  const int deg = rowstart[n + 1] - start;
  const int hh = lane >> 4;
  const int ch2 = lane << 1;                    // ushort offset within a row
  float2 acc = {0.f, 0.f};
  float ssel;
  if (deg <= 64) {
    int p = 0;
    float w0 = 0.f, w1 = 0.f, w2 = 0.f, w3 = 0.f;
    if (lane < deg) {
      p = eord[start + lane];
      int s = p & 0xffff, r = p >> 16;
      float4 k4 = kj4[r ? (NPAD + s) : s];
      float4 q4 = r ? qi4[NPAD + n] : qi4[n];
      w0 = __expf(fminf(lrelu(q4.x + k4.x), 85.f));
      w1 = __expf(fminf(lrelu(q4.y + k4.y), 85.f));
      w2 = __expf(fminf(lrelu(q4.z + k4.z), 85.f));
      w3 = __expf(fminf(lrelu(q4.w + k4.w), 85.f));
    }
    float s0 = w0, s1 = w1, s2 = w2, s3 = w3;
#pragma unroll
    for (int off = 32; off > 0; off >>= 1) {
      s0 += __shfl_xor(s0, off); s1 += __shfl_xor(s1, off);
      s2 += __shfl_xor(s2, off); s3 += __shfl_xor(s3, off);
    }
    ssel = hh == 0 ? s0 : hh == 1 ? s1 : hh == 2 ? s2 : s3;
    wls[wave][0][lane] = w0;
    wls[wave][1][lane] = w1;
    wls[wave][2][lane] = w2;
    wls[wave][3][lane] = w3;
    volatile const float* wrh = &wls[wave][hh][0];   // broadcast reads
    const int degp = (deg + 15) & ~15;          // pad lanes: w=0, p=0 (row 0, L1-hot)
#pragma unroll 1
    for (int e = 0; e < degp; e += 16) {
      int pp[16];
      unsigned vv[16];
#pragma unroll
      for (int u = 0; u < 16; ++u)
        pp[u] = __builtin_amdgcn_readlane(p, e + u);
#pragma unroll
      for (int u = 0; u < 16; ++u)
        vv[u] = *(const unsigned*)(xw + ((size_t)((pp[u] & 0xffff) + (pp[u] >> 16) * NPAD) << 7) + ch2);
#pragma unroll
      for (int u = 0; u < 16; ++u) {
        float we = wrh[e + u];
        acc.x = fmaf(lo_f(vv[u]), we, acc.x);
        acc.y = fmaf(hi_f(vv[u]), we, acc.y);
      }
    }
  } else {
    // ---- generic fallback (deg > 64): wave-uniform serial, rare ----
    const float4 q0 = qi4[n], q1 = qi4[NPAD + n];
    float4 m = make_float4(-1e30f, -1e30f, -1e30f, -1e30f);
    for (int e = start; e < start + deg; ++e) {
      int pe = eord[e];
      int s = pe & 0xffff, r = pe >> 16;
      float4 k4 = kj4[(size_t)r * NPAD + s];
      float4 q4 = r ? q1 : q0;
      m.x = fmaxf(m.x, lrelu(q4.x + k4.x)); m.y = fmaxf(m.y, lrelu(q4.y + k4.y));
      m.z = fmaxf(m.z, lrelu(q4.z + k4.z)); m.w = fmaxf(m.w, lrelu(q4.w + k4.w));
    }
    float4 sv = make_float4(0.f, 0.f, 0.f, 0.f);
    for (int e = start; e < start + deg; ++e) {
      int pe = eord[e];
      int s = pe & 0xffff, r = pe >> 16;
      float4 k4 = kj4[(size_t)r * NPAD + s];
      float4 q4 = r ? q1 : q0;
      float w0 = __expf(lrelu(q4.x + k4.x) - m.x);
      float w1 = __expf(lrelu(q4.y + k4.y) - m.y);
      float w2 = __expf(lrelu(q4.z + k4.z) - m.z);
      float w3 = __expf(lrelu(q4.w + k4.w) - m.w);
      sv.x += w0; sv.y += w1; sv.z += w2; sv.w += w3;
      float we = hh == 0 ? w0 : hh == 1 ? w1 : hh == 2 ? w2 : w3;
      unsigned v = *(const unsigned*)(xw + (((size_t)r * NPAD + s) << 7) + ch2);
      acc.x = fmaf(lo_f(v), we, acc.x);
      acc.y = fmaf(hi_f(v), we, acc.y);
    }
    ssel = hh == 0 ? sv.x : hh == 1 ? sv.y : hh == 2 ? sv.z : sv.w;
  }
  float inv = 1.f / (ssel + 1e-16f);
  *outp = (unsigned)f2bf_bits(acc.x * inv) | ((unsigned)f2bf_bits(acc.y * inv) << 16);
}

// ---- both layers: pWTb2 + folded bias ----
__global__ __launch_bounds__(64) void prep_proj_kernel(const void* __restrict__ pW0,
                                                       const void* __restrict__ pW1,
                                                       const float* __restrict__ cbf,
                                                       const float* __restrict__ pbf,
                                                       unsigned short* __restrict__ pWTb2,
                                                       float* __restrict__ bo2,
                                                       const int* __restrict__ flags) {
  int o = blockIdx.x & 127, l = blockIdx.x >> 7, t = threadIdx.x;
  const void* pWraw = l ? pW1 : pW0;
  const float* cb = cbf + l * HID;
  const int f = flags[0];
  float part = 0.f;
#pragma unroll
  for (int i = t; i < HID; i += 64) {
    float w = f ? ((const float*)pWraw)[o * HID + i] : bf2f(((const unsigned short*)pWraw)[o * HID + i]);
    pWTb2[(size_t)l * HID * HID + o * HID + i] = f2bf_bits(w);
    part += cb[i] * w;
  }
#pragma unroll
  for (int off = 32; off > 0; off >>= 1) part += __shfl_xor(part, off);
  if (t == 0) bo2[l * HID + o] = pbf[l * HID + o] + part;
}

extern "C" void kernel_launch(void* const* d_in, const int* in_sizes, int n_in,
                              void* d_out, int out_size, void* d_ws, size_t ws_size,
                              hipStream_t stream) {
  const void* x     = d_in[0];
  const int*  eidx  = (const int*)d_in[1];
  const int*  etype = (const int*)d_in[2];
  const int iW[2] = {3, 9}, iQ[2] = {4, 10}, iK[2] = {5, 11}, icb[2] = {6, 12}, ipW[2] = {7, 13}, ipb[2] = {8, 14};

  float* ws = (float*)d_ws;
  size_t off = 0;
  int*   flags = (int*)(ws + off); off += 16;
  unsigned short* hb   = (unsigned short*)(ws + off); off += (size_t)NPAD * HID / 2;
  unsigned short* xw   = (unsigned short*)(ws + off); off += (size_t)NPAD * HID;       // [2][NPAD][128] bf16
  float* qi   = ws + off; off += (size_t)2 * NPAD * HEADS;
  float* kj   = ws + off; off += (size_t)2 * NPAD * HEADS;
  unsigned short* aggb = (unsigned short*)(ws + off); off += (size_t)NPAD * HID / 2;
  int* dstA = (int*)(ws + off); off += E_EDGES;
  int* pk   = (int*)(ws + off); off += E_EDGES;
  int* eord = (int*)(ws + off); off += E_EDGES;
  int* deg  = (int*)(ws + off); off += NPAD;        // deg|cnt|bcnt contiguous for one zero pass
  int* cnt  = (int*)(ws + off); off += NPAD;
  int* bcnt = (int*)(ws + off); off += 16;
  int* excl = (int*)(ws + off); off += NPAD;
  int* rowstart = (int*)(ws + off); off += NPAD + 16;
  int* bsum  = (int*)(ws + off); off += 256;
  int* nq   = (int*)(ws + off); off += NPAD;
  int* nwl  = (int*)(ws + off); off += NPAD;
  unsigned short* Wbt   = (unsigned short*)(ws + off); off += (size_t)2 * 2 * HID * HID / 2;
  unsigned short* pWTb2 = (unsigned short*)(ws + off); off += (size_t)2 * HID * HID / 2;
  unsigned short* qkt_hi = (unsigned short*)(ws + off); off += (size_t)2 * 16 * HID / 2;
  unsigned short* qkt_lo = (unsigned short*)(ws + off); off += (size_t)2 * 16 * HID / 2;
  float* Qf  = ws + off; off += 2 * HID * HEADS;
  float* Kf  = ws + off; off += 2 * HID * HEADS;
  float* cbf = ws + off; off += 2 * HID;
  float* pbf = ws + off; off += 2 * HID;
  float* bo2 = ws + off; off += 2 * HID;

  // ---- detect + zero (fused) + convert ----
  detect_zero_kernel<<<(2 * NPAD + 16 + 255) / 256, 256, 0, stream>>>((const unsigned short*)x, eidx, flags, deg, 2 * NPAD + 16);
  cvt_idx_hist_kernel<<<(E_EDGES + 255) / 256, 256, 0, stream>>>(eidx, etype, dstA, pk, deg, flags);
  bucket_kernel<<<(N_NODES + 255) / 256, 256, 0, stream>>>(deg, bcnt, nq, nwl);
  cvt_xb_kernel<<<(N_NODES * HID / 8 + 255) / 256, 256, 0, stream>>>(x, hb, N_NODES * HID / 8, flags);
  cvt_wt_kernel<<<(2 * 2 * HID * HID + 255) / 256, 256, 0, stream>>>(d_in[iW[0]], d_in[iW[1]], Wbt, flags);
  {
    P8 tab;
    float* base = ws;
    for (int l = 0; l < 2; ++l) {
      tab.src[l * 4 + 0] = d_in[iQ[l]];  tab.dstoff[l * 4 + 0] = (int)(Qf - base) + l * HID * HEADS;  tab.n[l * 4 + 0] = HID * HEADS;
      tab.src[l * 4 + 1] = d_in[iK[l]];  tab.dstoff[l * 4 + 1] = (int)(Kf - base) + l * HID * HEADS;  tab.n[l * 4 + 1] = HID * HEADS;
      tab.src[l * 4 + 2] = d_in[icb[l]]; tab.dstoff[l * 4 + 2] = (int)(cbf - base) + l * HID;         tab.n[l * 4 + 2] = HID;
      tab.src[l * 4 + 3] = d_in[ipb[l]]; tab.dstoff[l * 4 + 3] = (int)(pbf - base) + l * HID;         tab.n[l * 4 + 3] = HID;
    }
    cvt_params_kernel<<<2, 256, 0, stream>>>(tab, base, flags);
  }

  // ---- counting sort by dst ----
  scan1_kernel<<<SCAN_B, 256, 0, stream>>>(deg, excl, bsum);
  scan23_kernel<<<SCAN_B, 256, 0, stream>>>(excl, bsum, rowstart);
  scatter_kernel<<<(E_EDGES + 255) / 256, 256, 0, stream>>>(dstA, pk, rowstart, cnt, eord);

  // ---- folded params ----
  prep_wq_kernel<<<2, 256, 0, stream>>>(Wbt, Qf, Kf, qkt_hi, qkt_lo);
  prep_proj_kernel<<<2 * HID, 64, 0, stream>>>(d_in[ipW[0]], d_in[ipW[1]], cbf, pbf, pWTb2, bo2, flags);

  const int RB = NPAD / 64;   // 782 row-blocks
  const int QB = (NPAD + 255) / 256;
  for (int l = 0; l < 2; ++l) {
    gemm_xw_mfma<<<RB, 256, 0, stream>>>(hb, Wbt + (size_t)l * 2 * HID * HID, xw);
    qk_mfma_kernel<<<QB, 256, 0, stream>>>(hb, qkt_hi + (size_t)l * 16 * HID, qkt_lo + (size_t)l * 16 * HID,
                                           (float4*)qi, (float4*)kj);
    edge_quad_kernel<<<(N_NODES + 15) / 16, 256, 0, stream>>>(rowstart, eord, (const float4*)qi, (const float4*)kj,
                                                              xw, aggb, nq, bcnt);
    edge_big_kernel<<<(N_NODES + 3) / 4, 256, 0, stream>>>(rowstart, eord, (const float4*)qi, (const float4*)kj,
                                                           xw, aggb, nwl, bcnt);
    proj_mfma<<<RB, 128, 0, stream>>>(aggb, pWTb2 + (size_t)l * HID * HID, bo2 + l * HID, hb,
                                      (l == 1) ? d_out : nullptr, flags);
  }
}

// Round 5
// 343.570 us; speedup vs baseline: 2.5390x; 1.0896x over previous
//
#include <hip/hip_runtime.h>
#include <hip/hip_bf16.h>

typedef __hip_bfloat16 bf16;
typedef short s16x8 __attribute__((ext_vector_type(8)));
typedef float f32x4 __attribute__((ext_vector_type(4)));

#define N_NODES 50000
#define NPAD    50048          // multiple of 64
#define E_EDGES 600000
#define HID     128
#define HEADS   4
#define SCAN_B  196            // ceil(NPAD/256)

// fused-dispatch block ranges
#define GB_IDX  2344           // ceil(E/256)
#define GB_XB   3125           // N*HID/8/256
#define GB_WT   256
#define GB_QUAD 3125           // ceil(N/16)
#define GB_BIG  8824           // ceil((E/17)/4) worst-case deg>16 nodes
#define GB_GEMM 1564           // NPAD/32
#define GB_QK   196

// ---- float -> bf16 bits (RNE), finite inputs only ----
__device__ __forceinline__ unsigned short f2bf_bits(float f) {
  unsigned u = __float_as_uint(f);
  u += 0x7fffu + ((u >> 16) & 1u);
  return (unsigned short)(u >> 16);
}
__device__ __forceinline__ float bf2f(unsigned short b) {
  return __uint_as_float(((unsigned)b) << 16);
}
__device__ __forceinline__ float lo_f(unsigned v) { return __uint_as_float(v << 16); }
__device__ __forceinline__ float hi_f(unsigned v) { return __uint_as_float(v & 0xffff0000u); }
__device__ __forceinline__ float lrelu(float v) { return fmaxf(v, 0.2f * v); }
__device__ __forceinline__ float elu(float v) { return v > 0.f ? v : __expf(v) - 1.f; }

// ---- runtime dtype detection + zero (fused: one dispatch) ----
__global__ __launch_bounds__(256) void detect_zero_kernel(const unsigned short* __restrict__ xb,
                                                          const int* __restrict__ ei,
                                                          int* __restrict__ flags,
                                                          int* __restrict__ zp, int nz) {
  int t = threadIdx.x;
  int i = blockIdx.x * 256 + t;
  if (i < nz) zp[i] = 0;
  if (blockIdx.x == 0) {
    __shared__ int cnt[2];
    if (t < 2) cnt[t] = 0;
    __syncthreads();
    unsigned short v = xb[2 * t];
    int ex = (v >> 7) & 0xFF;
    if (ex < 119 || ex > 135) atomicAdd(&cnt[0], 1);
    if (ei[2 * t + 1] != 0) atomicAdd(&cnt[1], 1);
    __syncthreads();
    if (t == 0) {
      flags[0] = (cnt[0] > 64) ? 1 : 0;
      flags[1] = (cnt[1] == 0) ? 1 : 0;
    }
  }
}

// ---- fused converts: {idx+hist | xb | wt | params} by block range ----
struct P8 { const void* src[8]; int dstoff[8]; int n[8]; };
__global__ __launch_bounds__(256) void cvt_all_kernel(const int* __restrict__ eidx,
                                                      const int* __restrict__ etype,
                                                      int* __restrict__ dstA, int* __restrict__ pk,
                                                      int* __restrict__ deg,
                                                      const void* __restrict__ x,
                                                      unsigned short* __restrict__ hb,
                                                      const void* __restrict__ w0,
                                                      const void* __restrict__ w1,
                                                      unsigned short* __restrict__ Wbt,
                                                      P8 tab, float* __restrict__ base,
                                                      const int* __restrict__ flags) {
  const int b = blockIdx.x, t = threadIdx.x;
  if (b < GB_IDX) {
    int e = b * 256 + t;
    if (e >= E_EDGES) return;
    int s, d, r;
    if (flags[1]) {
      const long long* e64 = (const long long*)eidx;
      const long long* t64 = (const long long*)etype;
      s = (int)e64[e]; d = (int)e64[E_EDGES + e]; r = (int)t64[e];
    } else {
      s = eidx[e]; d = eidx[E_EDGES + e]; r = etype[e];
    }
    dstA[e] = d;
    pk[e] = s | (r << 16);
    atomicAdd(&deg[d], 1);
  } else if (b < GB_IDX + GB_XB) {
    int i = (b - GB_IDX) * 256 + t;           // 8 bf16 per thread
    if (flags[0]) {
      const float4* s4 = (const float4*)x;
      float4 a = s4[2 * i], c = s4[2 * i + 1];
      s16x8 o;
      o[0] = (short)f2bf_bits(a.x); o[1] = (short)f2bf_bits(a.y);
      o[2] = (short)f2bf_bits(a.z); o[3] = (short)f2bf_bits(a.w);
      o[4] = (short)f2bf_bits(c.x); o[5] = (short)f2bf_bits(c.y);
      o[6] = (short)f2bf_bits(c.z); o[7] = (short)f2bf_bits(c.w);
      *(s16x8*)(hb + (size_t)i * 8) = o;
    } else {
      *(s16x8*)(hb + (size_t)i * 8) = ((const s16x8*)x)[i];
    }
  } else if (b < GB_IDX + GB_XB + GB_WT) {
    int idx = (b - GB_IDX - GB_XB) * 256 + t;
    int l = idx >> 15, rem = idx & 32767;
    int r = rem >> 14, i = (rem >> 7) & 127, o = rem & 127;
    const void* src = l ? w1 : w0;
    unsigned short v;
    if (flags[0]) v = f2bf_bits(((const float*)src)[rem]);
    else          v = ((const unsigned short*)src)[rem];
    Wbt[(size_t)l * 2 * HID * HID + ((size_t)r * HID + o) * HID + i] = v;
  } else {
    const int f = flags[0];
    int bb = b - GB_IDX - GB_XB - GB_WT;      // 0..1
    for (int k = 0; k < 8; ++k) {
      int n = tab.n[k];
      for (int i = bb * 256 + t; i < n; i += 2 * 256) {
        float v = f ? ((const float*)tab.src[k])[i] : bf2f(((const unsigned short*)tab.src[k])[i]);
        base[tab.dstoff[k] + i] = v;
      }
    }
  }
}

// ---- fused: scan stage 1 + degree bucketing ----
__global__ __launch_bounds__(256) void scan1_bucket_kernel(const int* __restrict__ deg,
                                                           int* __restrict__ excl,
                                                           int* __restrict__ bsum,
                                                           int* __restrict__ bcnt,
                                                           int* __restrict__ nq,
                                                           int* __restrict__ nw) {
  const int b = blockIdx.x, t = threadIdx.x;
  if (b < SCAN_B) {
    __shared__ int sm[256];
    int i = b * 256 + t;
    int v = (i < NPAD) ? deg[i] : 0;
    sm[t] = v;
    __syncthreads();
#pragma unroll
    for (int off = 1; off < 256; off <<= 1) {
      int add = (t >= off) ? sm[t - off] : 0;
      __syncthreads();
      sm[t] += add;
      __syncthreads();
    }
    if (i < NPAD) excl[i] = sm[t] - v;
    if (t == 255) bsum[b] = sm[255];
  } else {
    int n = (b - SCAN_B) * 256 + t;
    int lane = t & 63;
    bool valid = n < N_NODES;
    int d = valid ? deg[n] : 0;
    bool isq = valid && (d <= 16);
    bool isw = valid && (d > 16);
    unsigned long long mq = __ballot(isq);
    unsigned long long mw = __ballot(isw);
    unsigned long long lower = (lane == 63) ? 0x7fffffffffffffffull : ((1ull << lane) - 1ull);
    int baseq = 0, basew = 0;
    int lq = (int)__ffsll(mq) - 1;
    int lw = (int)__ffsll(mw) - 1;
    if (mq && lane == lq) baseq = atomicAdd(&bcnt[0], (int)__popcll(mq));
    if (mw && lane == lw) basew = atomicAdd(&bcnt[1], (int)__popcll(mw));
    if (mq) baseq = __shfl(baseq, lq);
    if (mw) basew = __shfl(basew, lw);
    if (isq) nq[baseq + (int)__popcll(mq & lower)] = n;
    if (isw) nw[basew + (int)__popcll(mw & lower)] = n;
  }
}

// ---- fused: scan stages 2+3 + WQ/WK fold + proj-weight prep ----
__global__ __launch_bounds__(256) void scan23_prep_kernel(const int* __restrict__ excl,
                                                          const int* __restrict__ bsum,
                                                          int* __restrict__ rowstart,
                                                          const unsigned short* __restrict__ Wbt,
                                                          const float* __restrict__ Qf,
                                                          const float* __restrict__ Kf,
                                                          unsigned short* __restrict__ qkt_hi,
                                                          unsigned short* __restrict__ qkt_lo,
                                                          const void* __restrict__ pW0,
                                                          const void* __restrict__ pW1,
                                                          const float* __restrict__ cbf,
                                                          const float* __restrict__ pbf,
                                                          unsigned short* __restrict__ pWTb2,
                                                          float* __restrict__ bo2,
                                                          const int* __restrict__ flags) {
  const int b = blockIdx.x, t = threadIdx.x;
  if (b < SCAN_B) {
    __shared__ int sm[256];
    int v = (t < SCAN_B) ? bsum[t] : 0;
    sm[t] = v;
    __syncthreads();
#pragma unroll
    for (int off = 1; off < 256; off <<= 1) {
      int add = (t >= off) ? sm[t - off] : 0;
      __syncthreads();
      sm[t] += add;
      __syncthreads();
    }
    int bpre = (b > 0) ? sm[b - 1] : 0;
    int i = b * 256 + t;
    if (i < NPAD) rowstart[i] = excl[i] + bpre;
    if (i == 0) rowstart[NPAD] = E_EDGES;
  } else if (b < SCAN_B + 2) {
    int idx = (b - SCAN_B) * 256 + t;         // (l,r,i)
    int i = idx & 127, lr = idx >> 7, l = lr >> 1, r = (lr & 1);
    float aq[4] = {0.f, 0.f, 0.f, 0.f}, ak[4] = {0.f, 0.f, 0.f, 0.f};
    const unsigned short* Wb = Wbt + (size_t)lr * HID * HID;   // [o=j][i]
    const float* Qp = Qf + l * HID * HEADS;
    const float* Kp = Kf + l * HID * HEADS;
    for (int j = 0; j < HID; ++j) {
      float w = bf2f(Wb[j * HID + i]);
      float4 q4 = *(const float4*)(Qp + j * 4);
      float4 k4 = *(const float4*)(Kp + j * 4);
      aq[0] += w * q4.x; aq[1] += w * q4.y; aq[2] += w * q4.z; aq[3] += w * q4.w;
      ak[0] += w * k4.x; ak[1] += w * k4.y; ak[2] += w * k4.z; ak[3] += w * k4.w;
    }
    size_t base = (size_t)l * 16 * HID;
#pragma unroll
    for (int h = 0; h < 4; ++h) {
      unsigned short qh = f2bf_bits(aq[h]);
      unsigned short kh = f2bf_bits(ak[h]);
      float qres = aq[h] - bf2f(qh);
      float kres = ak[h] - bf2f(kh);
      qkt_hi[base + (size_t)(r * 4 + h) * HID + i] = qh;
      qkt_lo[base + (size_t)(r * 4 + h) * HID + i] = f2bf_bits(qres);
      qkt_hi[base + (size_t)(8 + r * 4 + h) * HID + i] = kh;
      qkt_lo[base + (size_t)(8 + r * 4 + h) * HID + i] = f2bf_bits(kres);
    }
  } else {
    // prep_proj: one wave per (l,o); 64 blocks x 4 waves = 256 o-slots
    const int wave = t >> 6, lane = t & 63;
    int ob = (b - SCAN_B - 2) * 4 + wave;     // 0..255
    int o = ob & 127, l = ob >> 7;
    const void* pWraw = l ? pW1 : pW0;
    const float* cb = cbf + l * HID;
    const int f = flags[0];
    float part = 0.f;
#pragma unroll
    for (int i = lane; i < HID; i += 64) {
      float w = f ? ((const float*)pWraw)[o * HID + i] : bf2f(((const unsigned short*)pWraw)[o * HID + i]);
      pWTb2[(size_t)l * HID * HID + o * HID + i] = f2bf_bits(w);
      part += cb[i] * w;
    }
#pragma unroll
    for (int off = 32; off > 0; off >>= 1) part += __shfl_xor(part, off);
    if (lane == 0) bo2[l * HID + o] = pbf[l * HID + o] + part;
  }
}

__global__ __launch_bounds__(256) void scatter_kernel(const int* __restrict__ dstA,
                                                      const int* __restrict__ pk,
                                                      const int* __restrict__ rowstart,
                                                      int* __restrict__ cnt,
                                                      int* __restrict__ eord) {
  int e = blockIdx.x * 256 + threadIdx.x;
  if (e >= E_EDGES) return;
  int d = dstA[e];
  int pos = rowstart[d] + atomicAdd(&cnt[d], 1);
  eord[pos] = pk[e];
}

// ====== fused gemm_xw (32-row blocks) + qk (unchanged) ======
__global__ __launch_bounds__(256) void gemm_qk_kernel(const unsigned short* __restrict__ hb,
                                                      const unsigned short* __restrict__ Wbt,
                                                      unsigned short* __restrict__ xw,
                                                      const unsigned short* __restrict__ qkt_hi,
                                                      const unsigned short* __restrict__ qkt_lo,
                                                      float4* __restrict__ qi4,
                                                      float4* __restrict__ kj4) {
  __shared__ unsigned short smem[8704];       // 17408 B, shared by both paths
  const int t = threadIdx.x;
  const int wave = t >> 6, lane = t & 63;
  const int lm = lane & 15, q = lane >> 4;
  if (blockIdx.x < GB_GEMM) {
    // ---- gemm_xw: 32 rows/block, 4 waves = (r, colpanel) ----
    unsigned short (*As)[136] = (unsigned short(*)[136])smem;   // [32][136]
    const int row0 = blockIdx.x * 32;
    const int r = wave >> 1, colb = (wave & 1) * 64;
    const unsigned short* Bt = Wbt + (size_t)r * HID * HID;
    s16x8 bfr[4][4];
#pragma unroll
    for (int kc = 0; kc < 4; ++kc) {
      const int ko = kc * 32 + q * 8;
#pragma unroll
      for (int ct = 0; ct < 4; ++ct)
        bfr[kc][ct] = *(const s16x8*)(Bt + (size_t)(colb + ct * 16 + lm) * HID + ko);
    }
    const unsigned short* gsrc = hb + (size_t)row0 * HID;
#pragma unroll
    for (int j = 0; j < 2; ++j) {
      int idx = j * 256 + t;                  // 512 16B units
      *(s16x8*)&As[idx >> 4][(idx & 15) * 8] = *(const s16x8*)(gsrc + idx * 8);
    }
    __syncthreads();
    f32x4 acc[2][4];
#pragma unroll
    for (int a = 0; a < 2; ++a)
#pragma unroll
      for (int c = 0; c < 4; ++c) { f32x4 z = {0.f, 0.f, 0.f, 0.f}; acc[a][c] = z; }
#pragma unroll
    for (int kc = 0; kc < 4; ++kc) {
      const int ko = kc * 32 + q * 8;
#pragma unroll
      for (int rt = 0; rt < 2; ++rt) {
        s16x8 a = *(const s16x8*)&As[rt * 16 + lm][ko];
#pragma unroll
        for (int ct = 0; ct < 4; ++ct)
          acc[rt][ct] = __builtin_amdgcn_mfma_f32_16x16x32_bf16(a, bfr[kc][ct], acc[rt][ct], 0, 0, 0);
      }
    }
    __syncthreads();
#pragma unroll
    for (int rr = 0; rr < 2; ++rr) {
      if (r == rr) {
#pragma unroll
        for (int rt = 0; rt < 2; ++rt)
#pragma unroll
          for (int i = 0; i < 4; ++i) {
            int rloc = rt * 16 + q * 4 + i;
#pragma unroll
            for (int ct = 0; ct < 4; ++ct)
              As[rloc][colb + ct * 16 + lm] = f2bf_bits(acc[rt][ct][i]);
          }
      }
      __syncthreads();
      unsigned short* dst = xw + ((size_t)rr * NPAD + row0) * HID;
#pragma unroll
      for (int j = 0; j < 2; ++j) {
        int idx = j * 256 + t;                // 512 16B units
        int rw = idx >> 4, cb8 = (idx & 15) * 8;
        if (row0 + rw < N_NODES)
          *(s16x8*)(dst + (size_t)rw * HID + cb8) = *(const s16x8*)&As[rw][cb8];
      }
      __syncthreads();
    }
  } else {
    // ---- qk: [64 nodes]x[16 outs] per wave, split-bf16 B ----
    float (*st)[16][68] = (float(*)[16][68])smem;               // [4][16][68]
    const int row0 = (blockIdx.x - GB_GEMM) * 256 + wave * 64;
    if (row0 < NPAD) {
      s16x8 bhi[4], blo[4], af[4][4];
#pragma unroll
      for (int kc = 0; kc < 4; ++kc) {
        const int ko = kc * 32 + q * 8;
        bhi[kc] = *(const s16x8*)(qkt_hi + (size_t)lm * HID + ko);
        blo[kc] = *(const s16x8*)(qkt_lo + (size_t)lm * HID + ko);
      }
#pragma unroll
      for (int kc = 0; kc < 4; ++kc) {
        const int ko = kc * 32 + q * 8;
#pragma unroll
        for (int rt = 0; rt < 4; ++rt)
          af[kc][rt] = *(const s16x8*)(hb + (size_t)(row0 + rt * 16 + lm) * HID + ko);
      }
      f32x4 acc[4];
#pragma unroll
      for (int a = 0; a < 4; ++a) { f32x4 z = {0.f, 0.f, 0.f, 0.f}; acc[a] = z; }
#pragma unroll
      for (int kc = 0; kc < 4; ++kc)
#pragma unroll
        for (int rt = 0; rt < 4; ++rt) {
          acc[rt] = __builtin_amdgcn_mfma_f32_16x16x32_bf16(af[kc][rt], bhi[kc], acc[rt], 0, 0, 0);
          acc[rt] = __builtin_amdgcn_mfma_f32_16x16x32_bf16(af[kc][rt], blo[kc], acc[rt], 0, 0, 0);
        }
#pragma unroll
      for (int rt = 0; rt < 4; ++rt)
        *(f32x4*)&st[wave][lm][rt * 16 + q * 4] = acc[rt];
    }
    __syncthreads();
    if (row0 < NPAD) {
      int n = row0 + lane;
      if (n < N_NODES) {
        float4 v;
        v.x = st[wave][0][lane]; v.y = st[wave][1][lane]; v.z = st[wave][2][lane]; v.w = st[wave][3][lane];
        qi4[n] = v;
        v.x = st[wave][4][lane]; v.y = st[wave][5][lane]; v.z = st[wave][6][lane]; v.w = st[wave][7][lane];
        qi4[NPAD + n] = v;
        v.x = st[wave][8][lane]; v.y = st[wave][9][lane]; v.z = st[wave][10][lane]; v.w = st[wave][11][lane];
        kj4[n] = v;
        v.x = st[wave][12][lane]; v.y = st[wave][13][lane]; v.z = st[wave][14][lane]; v.w = st[wave][15][lane];
        kj4[NPAD + n] = v;
      }
    }
  }
}

// ====== fused edge: quad (deg<=16) + big (deg>16) by block range ======
__global__ __launch_bounds__(256) void edge_all_kernel(
    const int* __restrict__ rowstart, const int* __restrict__ eord,
    const float4* __restrict__ qi4, const float4* __restrict__ kj4,
    const unsigned short* __restrict__ xw, unsigned short* __restrict__ aggb,
    const int* __restrict__ nq, const int* __restrict__ nw,
    const int* __restrict__ bcnt) {
  __shared__ volatile float wbuf[1152];       // quad: [16][4][17]=1088  big: [4][4][72]=1152
  const int t = threadIdx.x;
  const int wave = t >> 6, lane = t & 63;
  if (blockIdx.x < GB_QUAD) {
    // ---- quad: 4 nodes/wave, 16 lanes/node, 8 ch/lane ----
    const int g = lane >> 4, li = lane & 15;
    const int idx = blockIdx.x * 16 + wave * 4 + g;
    const int cq = bcnt[0];
    const bool act = idx < cq;
    const int n = act ? nq[idx] : 0;
    const int start = rowstart[n];
    const int dg = act ? (rowstart[n + 1] - start) : 0;
    int p = 0;
    float w0 = 0.f, w1 = 0.f, w2 = 0.f, w3 = 0.f;
    if (li < dg) {
      p = eord[start + li];
      int s = p & 0xffff, r = p >> 16;
      float4 k4 = kj4[r ? (NPAD + s) : s];
      float4 q4 = r ? qi4[NPAD + n] : qi4[n];
      w0 = __expf(fminf(lrelu(q4.x + k4.x), 85.f));
      w1 = __expf(fminf(lrelu(q4.y + k4.y), 85.f));
      w2 = __expf(fminf(lrelu(q4.z + k4.z), 85.f));
      w3 = __expf(fminf(lrelu(q4.w + k4.w), 85.f));
    }
    const int wg = (wave << 2) | g;
    volatile float* wls = &wbuf[wg * 68];     // [4][17]
    wls[0 * 17 + li] = w0; wls[1 * 17 + li] = w1;
    wls[2 * 17 + li] = w2; wls[3 * 17 + li] = w3;
    float s0 = w0, s1 = w1, s2 = w2, s3 = w3;
#pragma unroll
    for (int off = 8; off > 0; off >>= 1) {
      s0 += __shfl_xor(s0, off); s1 += __shfl_xor(s1, off);
      s2 += __shfl_xor(s2, off); s3 += __shfl_xor(s3, off);
    }
    const int hh = li >> 2;
    float ssel = hh == 0 ? s0 : hh == 1 ? s1 : hh == 2 ? s2 : s3;
    float a0 = 0.f, a1 = 0.f, a2 = 0.f, a3 = 0.f, a4 = 0.f, a5 = 0.f, a6 = 0.f, a7 = 0.f;
    volatile const float* wrh = &wls[hh * 17];
    const int co = li * 8;
    const int gbase = lane & 48;
#pragma unroll 1
    for (int e0 = 0; e0 < dg; e0 += 4) {
      int pe[4];
      uint4 v[4];
#pragma unroll
      for (int u = 0; u < 4; ++u) {
        int e = e0 + u;
        pe[u] = __shfl(p, gbase + (e < dg ? e : 0));
      }
#pragma unroll
      for (int u = 0; u < 4; ++u)
        v[u] = *(const uint4*)(xw + ((size_t)((pe[u] & 0xffff) + (pe[u] >> 16) * NPAD) << 7) + co);
#pragma unroll
      for (int u = 0; u < 4; ++u) {
        int e = e0 + u;
        float we = (e < dg) ? wrh[e] : 0.f;
        a0 = fmaf(lo_f(v[u].x), we, a0); a1 = fmaf(hi_f(v[u].x), we, a1);
        a2 = fmaf(lo_f(v[u].y), we, a2); a3 = fmaf(hi_f(v[u].y), we, a3);
        a4 = fmaf(lo_f(v[u].z), we, a4); a5 = fmaf(hi_f(v[u].z), we, a5);
        a6 = fmaf(lo_f(v[u].w), we, a6); a7 = fmaf(hi_f(v[u].w), we, a7);
      }
    }
    if (act) {
      float inv = 1.f / (ssel + 1e-16f);
      uint4 o;
      o.x = (unsigned)f2bf_bits(a0 * inv) | ((unsigned)f2bf_bits(a1 * inv) << 16);
      o.y = (unsigned)f2bf_bits(a2 * inv) | ((unsigned)f2bf_bits(a3 * inv) << 16);
      o.z = (unsigned)f2bf_bits(a4 * inv) | ((unsigned)f2bf_bits(a5 * inv) << 16);
      o.w = (unsigned)f2bf_bits(a6 * inv) | ((unsigned)f2bf_bits(a7 * inv) << 16);
      *(uint4*)(aggb + ((size_t)n << 7) + co) = o;
    }
  } else {
    // ---- big: one wave per node ----
    const int idx = (blockIdx.x - GB_QUAD) * 4 + wave;
    const int cw = bcnt[1];
    if (idx >= cw) return;
    const int n = nw[idx];
    unsigned* outp = (unsigned*)(aggb + ((size_t)n << 7)) + lane;
    const int start = rowstart[n];
    const int deg = rowstart[n + 1] - start;
    const int hh = lane >> 4;
    const int ch2 = lane << 1;
    float2 acc = {0.f, 0.f};
    float ssel;
    volatile float* wls = &wbuf[wave * 288];  // [4][72]
    if (deg <= 64) {
      int p = 0;
      float w0 = 0.f, w1 = 0.f, w2 = 0.f, w3 = 0.f;
      if (lane < deg) {
        p = eord[start + lane];
        int s = p & 0xffff, r = p >> 16;
        float4 k4 = kj4[r ? (NPAD + s) : s];
        float4 q4 = r ? qi4[NPAD + n] : qi4[n];
        w0 = __expf(fminf(lrelu(q4.x + k4.x), 85.f));
        w1 = __expf(fminf(lrelu(q4.y + k4.y), 85.f));
        w2 = __expf(fminf(lrelu(q4.z + k4.z), 85.f));
        w3 = __expf(fminf(lrelu(q4.w + k4.w), 85.f));
      }
      float s0 = w0, s1 = w1, s2 = w2, s3 = w3;
#pragma unroll
      for (int off = 32; off > 0; off >>= 1) {
        s0 += __shfl_xor(s0, off); s1 += __shfl_xor(s1, off);
        s2 += __shfl_xor(s2, off); s3 += __shfl_xor(s3, off);
      }
      ssel = hh == 0 ? s0 : hh == 1 ? s1 : hh == 2 ? s2 : s3;
      wls[0 * 72 + lane] = w0;
      wls[1 * 72 + lane] = w1;
      wls[2 * 72 + lane] = w2;
      wls[3 * 72 + lane] = w3;
      volatile const float* wrh = &wls[hh * 72];
      const int degp = (deg + 15) & ~15;
#pragma unroll 1
      for (int e = 0; e < degp; e += 16) {
        int pp[16];
        unsigned vv[16];
#pragma unroll
        for (int u = 0; u < 16; ++u)
          pp[u] = __builtin_amdgcn_readlane(p, e + u);
#pragma unroll
        for (int u = 0; u < 16; ++u)
          vv[u] = *(const unsigned*)(xw + ((size_t)((pp[u] & 0xffff) + (pp[u] >> 16) * NPAD) << 7) + ch2);
#pragma unroll
        for (int u = 0; u < 16; ++u) {
          float we = wrh[e + u];
          acc.x = fmaf(lo_f(vv[u]), we, acc.x);
          acc.y = fmaf(hi_f(vv[u]), we, acc.y);
        }
      }
    } else {
      const float4 q0 = qi4[n], q1 = qi4[NPAD + n];
      float4 m = make_float4(-1e30f, -1e30f, -1e30f, -1e30f);
      for (int e = start; e < start + deg; ++e) {
        int pe = eord[e];
        int s = pe & 0xffff, r = pe >> 16;
        float4 k4 = kj4[(size_t)r * NPAD + s];
        float4 q4 = r ? q1 : q0;
        m.x = fmaxf(m.x, lrelu(q4.x + k4.x)); m.y = fmaxf(m.y, lrelu(q4.y + k4.y));
        m.z = fmaxf(m.z, lrelu(q4.z + k4.z)); m.w = fmaxf(m.w, lrelu(q4.w + k4.w));
      }
      float4 sv = make_float4(0.f, 0.f, 0.f, 0.f);
      for (int e = start; e < start + deg; ++e) {
        int pe = eord[e];
        int s = pe & 0xffff, r = pe >> 16;
        float4 k4 = kj4[(size_t)r * NPAD + s];
        float4 q4 = r ? q1 : q0;
        float w0 = __expf(lrelu(q4.x + k4.x) - m.x);
        float w1 = __expf(lrelu(q4.y + k4.y) - m.y);
        float w2 = __expf(lrelu(q4.z + k4.z) - m.z);
        float w3 = __expf(lrelu(q4.w + k4.w) - m.w);
        sv.x += w0; sv.y += w1; sv.z += w2; sv.w += w3;
        float we = hh == 0 ? w0 : hh == 1 ? w1 : hh == 2 ? w2 : w3;
        unsigned v = *(const unsigned*)(xw + (((size_t)r * NPAD + s) << 7) + ch2);
        acc.x = fmaf(lo_f(v), we, acc.x);
        acc.y = fmaf(hi_f(v), we, acc.y);
      }
      ssel = hh == 0 ? sv.x : hh == 1 ? sv.y : hh == 2 ? sv.z : sv.w;
    }
    float inv = 1.f / (ssel + 1e-16f);
    *outp = (unsigned)f2bf_bits(acc.x * inv) | ((unsigned)f2bf_bits(acc.y * inv) << 16);
  }
}

// ---- proj: 64 rows/block, 4 waves = (rowhalf, colpanel), 32x64 per wave ----
__global__ __launch_bounds__(256) void proj_mfma(const unsigned short* __restrict__ aggb,
                                                 const unsigned short* __restrict__ pWTb,
                                                 const float* __restrict__ bo,
                                                 unsigned short* __restrict__ hbout,
                                                 void* __restrict__ dout,
                                                 const int* __restrict__ flags) {
  __shared__ unsigned short As[64][136];
  const int t = threadIdx.x;
  const int wave = t >> 6, lane = t & 63;
  const int row0 = blockIdx.x * 64;
  const int h = wave >> 1;                    // rows h*32 .. h*32+31 (tiles 2h, 2h+1)
  const int colb = (wave & 1) * 64;
  const int lm = lane & 15, q = lane >> 4;
  s16x8 bfr[4][4];
#pragma unroll
  for (int kc = 0; kc < 4; ++kc) {
    const int ko = kc * 32 + q * 8;
#pragma unroll
    for (int ct = 0; ct < 4; ++ct)
      bfr[kc][ct] = *(const s16x8*)(pWTb + (size_t)(colb + ct * 16 + lm) * HID + ko);
  }
  const unsigned short* gsrc = aggb + (size_t)row0 * HID;
#pragma unroll
  for (int j = 0; j < 4; ++j) {
    int idx = j * 256 + t;                    // 1024 16B units
    *(s16x8*)&As[idx >> 4][(idx & 15) * 8] = *(const s16x8*)(gsrc + idx * 8);
  }
  __syncthreads();
  f32x4 acc[2][4];
#pragma unroll
  for (int a = 0; a < 2; ++a)
#pragma unroll
    for (int c = 0; c < 4; ++c) { f32x4 z = {0.f, 0.f, 0.f, 0.f}; acc[a][c] = z; }
#pragma unroll
  for (int kc = 0; kc < 4; ++kc) {
    const int ko = kc * 32 + q * 8;
#pragma unroll
    for (int rt = 0; rt < 2; ++rt) {
      s16x8 a = *(const s16x8*)&As[(2 * h + rt) * 16 + lm][ko];
#pragma unroll
      for (int ct = 0; ct < 4; ++ct)
        acc[rt][ct] = __builtin_amdgcn_mfma_f32_16x16x32_bf16(a, bfr[kc][ct], acc[rt][ct], 0, 0, 0);
    }
  }
  __syncthreads();
  const int f32final = (dout != nullptr) && flags[0];
  if (!f32final) {
    unsigned short* dstp = dout ? (unsigned short*)dout : hbout;
#pragma unroll
    for (int rt = 0; rt < 2; ++rt)
#pragma unroll
      for (int i = 0; i < 4; ++i) {
        int rloc = (2 * h + rt) * 16 + q * 4 + i;
#pragma unroll
        for (int ct = 0; ct < 4; ++ct) {
          int o = colb + ct * 16 + lm;
          float v = elu(acc[rt][ct][i] + bo[o]);
          As[rloc][o] = f2bf_bits(v);
        }
      }
    __syncthreads();
#pragma unroll
    for (int j = 0; j < 4; ++j) {
      int idx = j * 256 + t;                  // 1024 16B units
      int rw = idx >> 4, cb8 = (idx & 15) * 8;
      if (row0 + rw < N_NODES)
        *(s16x8*)(dstp + (size_t)(row0 + rw) * HID + cb8) = *(const s16x8*)&As[rw][cb8];
    }
  } else {
    float* fdst = (float*)dout;
    float (*Fs)[132] = (float(*)[132])&As[0][0];   // 32*132*4 = 16896 B <= 17408
#pragma unroll
    for (int h2 = 0; h2 < 2; ++h2) {
      if (h == h2) {
#pragma unroll
        for (int rt = 0; rt < 2; ++rt)
#pragma unroll
          for (int i = 0; i < 4; ++i) {
            int rloc = rt * 16 + q * 4 + i;
#pragma unroll
            for (int ct = 0; ct < 4; ++ct) {
              int o = colb + ct * 16 + lm;
              Fs[rloc][o] = elu(acc[rt][ct][i] + bo[o]);
            }
          }
      }
      __syncthreads();
#pragma unroll
      for (int j = 0; j < 4; ++j) {
        int idx = j * 256 + t;                // 1024 float4 units (32 rows x 32)
        int rw = idx >> 5, cb4 = (idx & 31) * 4;
        if (row0 + h2 * 32 + rw < N_NODES)
          *(float4*)(fdst + (size_t)(row0 + h2 * 32 + rw) * HID + cb4) = *(const float4*)&Fs[rw][cb4];
      }
      __syncthreads();
    }
  }
}

extern "C" void kernel_launch(void* const* d_in, const int* in_sizes, int n_in,
                              void* d_out, int out_size, void* d_ws, size_t ws_size,
                              hipStream_t stream) {
  const void* x     = d_in[0];
  const int*  eidx  = (const int*)d_in[1];
  const int*  etype = (const int*)d_in[2];
  const int iW[2] = {3, 9}, iQ[2] = {4, 10}, iK[2] = {5, 11}, icb[2] = {6, 12}, ipW[2] = {7, 13}, ipb[2] = {8, 14};

  float* ws = (float*)d_ws;
  size_t off = 0;
  int*   flags = (int*)(ws + off); off += 16;
  unsigned short* hb   = (unsigned short*)(ws + off); off += (size_t)NPAD * HID / 2;
  unsigned short* xw   = (unsigned short*)(ws + off); off += (size_t)NPAD * HID;       // [2][NPAD][128] bf16
  float* qi   = ws + off; off += (size_t)2 * NPAD * HEADS;
  float* kj   = ws + off; off += (size_t)2 * NPAD * HEADS;
  unsigned short* aggb = (unsigned short*)(ws + off); off += (size_t)NPAD * HID / 2;
  int* dstA = (int*)(ws + off); off += E_EDGES;
  int* pk   = (int*)(ws + off); off += E_EDGES;
  int* eord = (int*)(ws + off); off += E_EDGES;
  int* deg  = (int*)(ws + off); off += NPAD;        // deg|cnt|bcnt contiguous for one zero pass
  int* cnt  = (int*)(ws + off); off += NPAD;
  int* bcnt = (int*)(ws + off); off += 16;
  int* excl = (int*)(ws + off); off += NPAD;
  int* rowstart = (int*)(ws + off); off += NPAD + 16;
  int* bsum  = (int*)(ws + off); off += 256;
  int* nq   = (int*)(ws + off); off += NPAD;
  int* nwl  = (int*)(ws + off); off += NPAD;
  unsigned short* Wbt   = (unsigned short*)(ws + off); off += (size_t)2 * 2 * HID * HID / 2;
  unsigned short* pWTb2 = (unsigned short*)(ws + off); off += (size_t)2 * HID * HID / 2;
  unsigned short* qkt_hi = (unsigned short*)(ws + off); off += (size_t)2 * 16 * HID / 2;
  unsigned short* qkt_lo = (unsigned short*)(ws + off); off += (size_t)2 * 16 * HID / 2;
  float* Qf  = ws + off; off += 2 * HID * HEADS;
  float* Kf  = ws + off; off += 2 * HID * HEADS;
  float* cbf = ws + off; off += 2 * HID;
  float* pbf = ws + off; off += 2 * HID;
  float* bo2 = ws + off; off += 2 * HID;

  // D1: detect + zero deg|cnt|bcnt
  detect_zero_kernel<<<(2 * NPAD + 16 + 255) / 256, 256, 0, stream>>>((const unsigned short*)x, eidx, flags, deg, 2 * NPAD + 16);

  // D2: all converts (idx+hist | xb | wt | params)
  {
    P8 tab;
    float* base = ws;
    for (int l = 0; l < 2; ++l) {
      tab.src[l * 4 + 0] = d_in[iQ[l]];  tab.dstoff[l * 4 + 0] = (int)(Qf - base) + l * HID * HEADS;  tab.n[l * 4 + 0] = HID * HEADS;
      tab.src[l * 4 + 1] = d_in[iK[l]];  tab.dstoff[l * 4 + 1] = (int)(Kf - base) + l * HID * HEADS;  tab.n[l * 4 + 1] = HID * HEADS;
      tab.src[l * 4 + 2] = d_in[icb[l]]; tab.dstoff[l * 4 + 2] = (int)(cbf - base) + l * HID;         tab.n[l * 4 + 2] = HID;
      tab.src[l * 4 + 3] = d_in[ipb[l]]; tab.dstoff[l * 4 + 3] = (int)(pbf - base) + l * HID;         tab.n[l * 4 + 3] = HID;
    }
    cvt_all_kernel<<<GB_IDX + GB_XB + GB_WT + 2, 256, 0, stream>>>(eidx, etype, dstA, pk, deg,
                                                                   x, hb, d_in[iW[0]], d_in[iW[1]], Wbt,
                                                                   tab, ws, flags);
  }

  // D3: scan stage 1 + bucketing
  scan1_bucket_kernel<<<SCAN_B + SCAN_B, 256, 0, stream>>>(deg, excl, bsum, bcnt, nq, nwl);

  // D4: scan stages 2+3 + param folds
  scan23_prep_kernel<<<SCAN_B + 2 + 64, 256, 0, stream>>>(excl, bsum, rowstart,
                                                          Wbt, Qf, Kf, qkt_hi, qkt_lo,
                                                          d_in[ipW[0]], d_in[ipW[1]], cbf, pbf, pWTb2, bo2, flags);

  // D5: counting-sort scatter
  scatter_kernel<<<(E_EDGES + 255) / 256, 256, 0, stream>>>(dstA, pk, rowstart, cnt, eord);

  for (int l = 0; l < 2; ++l) {
    gemm_qk_kernel<<<GB_GEMM + GB_QK, 256, 0, stream>>>(hb, Wbt + (size_t)l * 2 * HID * HID, xw,
                                                        qkt_hi + (size_t)l * 16 * HID, qkt_lo + (size_t)l * 16 * HID,
                                                        (float4*)qi, (float4*)kj);
    edge_all_kernel<<<GB_QUAD + GB_BIG, 256, 0, stream>>>(rowstart, eord, (const float4*)qi, (const float4*)kj,
                                                          xw, aggb, nq, nwl, bcnt);
    proj_mfma<<<NPAD / 64, 256, 0, stream>>>(aggb, pWTb2 + (size_t)l * HID * HID, bo2 + l * HID, hb,
                                             (l == 1) ? d_out : nullptr, flags);
  }
}

// Round 6
// 343.115 us; speedup vs baseline: 2.5424x; 1.0013x over previous
//
#include <hip/hip_runtime.h>
#include <hip/hip_bf16.h>

typedef __hip_bfloat16 bf16;
typedef short s16x8 __attribute__((ext_vector_type(8)));
typedef float f32x4 __attribute__((ext_vector_type(4)));

#define N_NODES 50000
#define NPAD    50048          // multiple of 64
#define E_EDGES 600000
#define HID     128
#define HEADS   4
#define SCAN_B  196            // ceil(NPAD/256)

// fused-dispatch block ranges
#define GB_IDX  2344           // ceil(E/256)
#define GB_WT   256
#define GB_QUAD 3125           // ceil(N/16)
#define GB_BIG  8824           // ceil((E/17)/4) worst-case deg>16 nodes

// ---- float -> bf16 bits (RNE), finite inputs only ----
__device__ __forceinline__ unsigned short f2bf_bits(float f) {
  unsigned u = __float_as_uint(f);
  u += 0x7fffu + ((u >> 16) & 1u);
  return (unsigned short)(u >> 16);
}
__device__ __forceinline__ float bf2f(unsigned short b) {
  return __uint_as_float(((unsigned)b) << 16);
}
__device__ __forceinline__ float lo_f(unsigned v) { return __uint_as_float(v << 16); }
__device__ __forceinline__ float hi_f(unsigned v) { return __uint_as_float(v & 0xffff0000u); }
__device__ __forceinline__ float lrelu(float v) { return fmaxf(v, 0.2f * v); }
__device__ __forceinline__ float elu(float v) { return v > 0.f ? v : __expf(v) - 1.f; }

// ---- runtime dtype detection + zero (fused: one dispatch) ----
__global__ __launch_bounds__(256) void detect_zero_kernel(const unsigned short* __restrict__ xb,
                                                          const int* __restrict__ ei,
                                                          int* __restrict__ flags,
                                                          int* __restrict__ zp, int nz) {
  int t = threadIdx.x;
  int i = blockIdx.x * 256 + t;
  if (i < nz) zp[i] = 0;
  if (blockIdx.x == 0) {
    __shared__ int cnt[2];
    if (t < 2) cnt[t] = 0;
    __syncthreads();
    unsigned short v = xb[2 * t];
    int ex = (v >> 7) & 0xFF;
    if (ex < 119 || ex > 135) atomicAdd(&cnt[0], 1);
    if (ei[2 * t + 1] != 0) atomicAdd(&cnt[1], 1);
    __syncthreads();
    if (t == 0) {
      flags[0] = (cnt[0] > 64) ? 1 : 0;
      flags[1] = (cnt[1] == 0) ? 1 : 0;
    }
  }
}

// ---- fused converts: {idx+hist | wt | params} by block range ----
struct P8 { const void* src[8]; int dstoff[8]; int n[8]; };
__global__ __launch_bounds__(256) void cvt_all_kernel(const int* __restrict__ eidx,
                                                      const int* __restrict__ etype,
                                                      int* __restrict__ dstA, int* __restrict__ pk,
                                                      int* __restrict__ deg,
                                                      const void* __restrict__ w0,
                                                      const void* __restrict__ w1,
                                                      unsigned short* __restrict__ Wbt,
                                                      P8 tab, float* __restrict__ base,
                                                      const int* __restrict__ flags) {
  const int b = blockIdx.x, t = threadIdx.x;
  if (b < GB_IDX) {
    int e = b * 256 + t;
    if (e >= E_EDGES) return;
    int s, d, r;
    if (flags[1]) {
      const long long* e64 = (const long long*)eidx;
      const long long* t64 = (const long long*)etype;
      s = (int)e64[e]; d = (int)e64[E_EDGES + e]; r = (int)t64[e];
    } else {
      s = eidx[e]; d = eidx[E_EDGES + e]; r = etype[e];
    }
    dstA[e] = d;
    pk[e] = s | (r << 16);
    atomicAdd(&deg[d], 1);
  } else if (b < GB_IDX + GB_WT) {
    int idx = (b - GB_IDX) * 256 + t;
    int l = idx >> 15, rem = idx & 32767;
    int r = rem >> 14, i = (rem >> 7) & 127, o = rem & 127;
    const void* src = l ? w1 : w0;
    unsigned short v;
    if (flags[0]) v = f2bf_bits(((const float*)src)[rem]);
    else          v = ((const unsigned short*)src)[rem];
    Wbt[(size_t)l * 2 * HID * HID + ((size_t)r * HID + o) * HID + i] = v;
  } else {
    const int f = flags[0];
    int bb = b - GB_IDX - GB_WT;              // 0..1
    for (int k = 0; k < 8; ++k) {
      int n = tab.n[k];
      for (int i = bb * 256 + t; i < n; i += 2 * 256) {
        float v = f ? ((const float*)tab.src[k])[i] : bf2f(((const unsigned short*)tab.src[k])[i]);
        base[tab.dstoff[k] + i] = v;
      }
    }
  }
}

// ---- fused: scan stage 1 + degree bucketing ----
__global__ __launch_bounds__(256) void scan1_bucket_kernel(const int* __restrict__ deg,
                                                           int* __restrict__ excl,
                                                           int* __restrict__ bsum,
                                                           int* __restrict__ bcnt,
                                                           int* __restrict__ nq,
                                                           int* __restrict__ nw) {
  const int b = blockIdx.x, t = threadIdx.x;
  if (b < SCAN_B) {
    __shared__ int sm[256];
    int i = b * 256 + t;
    int v = (i < NPAD) ? deg[i] : 0;
    sm[t] = v;
    __syncthreads();
#pragma unroll
    for (int off = 1; off < 256; off <<= 1) {
      int add = (t >= off) ? sm[t - off] : 0;
      __syncthreads();
      sm[t] += add;
      __syncthreads();
    }
    if (i < NPAD) excl[i] = sm[t] - v;
    if (t == 255) bsum[b] = sm[255];
  } else {
    int n = (b - SCAN_B) * 256 + t;
    int lane = t & 63;
    bool valid = n < N_NODES;
    int d = valid ? deg[n] : 0;
    bool isq = valid && (d <= 16);
    bool isw = valid && (d > 16);
    unsigned long long mq = __ballot(isq);
    unsigned long long mw = __ballot(isw);
    unsigned long long lower = (lane == 63) ? 0x7fffffffffffffffull : ((1ull << lane) - 1ull);
    int baseq = 0, basew = 0;
    int lq = (int)__ffsll(mq) - 1;
    int lw = (int)__ffsll(mw) - 1;
    if (mq && lane == lq) baseq = atomicAdd(&bcnt[0], (int)__popcll(mq));
    if (mw && lane == lw) basew = atomicAdd(&bcnt[1], (int)__popcll(mw));
    if (mq) baseq = __shfl(baseq, lq);
    if (mw) basew = __shfl(basew, lw);
    if (isq) nq[baseq + (int)__popcll(mq & lower)] = n;
    if (isw) nw[basew + (int)__popcll(mw & lower)] = n;
  }
}

// ---- fused: scan stages 2+3 + WQ/WK fold + proj-weight prep ----
__global__ __launch_bounds__(256) void scan23_prep_kernel(const int* __restrict__ excl,
                                                          const int* __restrict__ bsum,
                                                          int* __restrict__ rowstart,
                                                          const unsigned short* __restrict__ Wbt,
                                                          const float* __restrict__ Qf,
                                                          const float* __restrict__ Kf,
                                                          unsigned short* __restrict__ qkt_hi,
                                                          unsigned short* __restrict__ qkt_lo,
                                                          const void* __restrict__ pW0,
                                                          const void* __restrict__ pW1,
                                                          const float* __restrict__ cbf,
                                                          const float* __restrict__ pbf,
                                                          unsigned short* __restrict__ pWTb2,
                                                          float* __restrict__ bo2,
                                                          const int* __restrict__ flags) {
  const int b = blockIdx.x, t = threadIdx.x;
  if (b < SCAN_B) {
    __shared__ int sm[256];
    int v = (t < SCAN_B) ? bsum[t] : 0;
    sm[t] = v;
    __syncthreads();
#pragma unroll
    for (int off = 1; off < 256; off <<= 1) {
      int add = (t >= off) ? sm[t - off] : 0;
      __syncthreads();
      sm[t] += add;
      __syncthreads();
    }
    int bpre = (b > 0) ? sm[b - 1] : 0;
    int i = b * 256 + t;
    if (i < NPAD) rowstart[i] = excl[i] + bpre;
    if (i == 0) rowstart[NPAD] = E_EDGES;
  } else if (b < SCAN_B + 2) {
    int idx = (b - SCAN_B) * 256 + t;         // (l,r,i)
    int i = idx & 127, lr = idx >> 7, l = lr >> 1, r = (lr & 1);
    float aq[4] = {0.f, 0.f, 0.f, 0.f}, ak[4] = {0.f, 0.f, 0.f, 0.f};
    const unsigned short* Wb = Wbt + (size_t)lr * HID * HID;   // [o=j][i]
    const float* Qp = Qf + l * HID * HEADS;
    const float* Kp = Kf + l * HID * HEADS;
    for (int j = 0; j < HID; ++j) {
      float w = bf2f(Wb[j * HID + i]);
      float4 q4 = *(const float4*)(Qp + j * 4);
      float4 k4 = *(const float4*)(Kp + j * 4);
      aq[0] += w * q4.x; aq[1] += w * q4.y; aq[2] += w * q4.z; aq[3] += w * q4.w;
      ak[0] += w * k4.x; ak[1] += w * k4.y; ak[2] += w * k4.z; ak[3] += w * k4.w;
    }
    size_t base = (size_t)l * 16 * HID;
#pragma unroll
    for (int h = 0; h < 4; ++h) {
      unsigned short qh = f2bf_bits(aq[h]);
      unsigned short kh = f2bf_bits(ak[h]);
      float qres = aq[h] - bf2f(qh);
      float kres = ak[h] - bf2f(kh);
      qkt_hi[base + (size_t)(r * 4 + h) * HID + i] = qh;
      qkt_lo[base + (size_t)(r * 4 + h) * HID + i] = f2bf_bits(qres);
      qkt_hi[base + (size_t)(8 + r * 4 + h) * HID + i] = kh;
      qkt_lo[base + (size_t)(8 + r * 4 + h) * HID + i] = f2bf_bits(kres);
    }
  } else {
    // prep_proj: one wave per (l,o); 64 blocks x 4 waves = 256 o-slots
    const int wave = t >> 6, lane = t & 63;
    int ob = (b - SCAN_B - 2) * 4 + wave;     // 0..255
    int o = ob & 127, l = ob >> 7;
    const void* pWraw = l ? pW1 : pW0;
    const float* cb = cbf + l * HID;
    const int f = flags[0];
    float part = 0.f;
#pragma unroll
    for (int i = lane; i < HID; i += 64) {
      float w = f ? ((const float*)pWraw)[o * HID + i] : bf2f(((const unsigned short*)pWraw)[o * HID + i]);
      pWTb2[(size_t)l * HID * HID + o * HID + i] = f2bf_bits(w);
      part += cb[i] * w;
    }
#pragma unroll
    for (int off = 32; off > 0; off >>= 1) part += __shfl_xor(part, off);
    if (lane == 0) bo2[l * HID + o] = pbf[l * HID + o] + part;
  }
}

__global__ __launch_bounds__(256) void scatter_kernel(const int* __restrict__ dstA,
                                                      const int* __restrict__ pk,
                                                      const int* __restrict__ rowstart,
                                                      int* __restrict__ cnt,
                                                      int* __restrict__ eord) {
  int e = blockIdx.x * 256 + threadIdx.x;
  if (e >= E_EDGES) return;
  int d = dstA[e];
  int pos = rowstart[d] + atomicAdd(&cnt[d], 1);
  eord[pos] = pk[e];
}

// ====== shared device helpers for the fused row-local kernels ======
// gemm body: As (64 rows bf16 in LDS) @ Wbt[r] -> xw, restaged through Cs.
__device__ __forceinline__ void gemm64_from_lds(unsigned short (*As)[136], unsigned short (*Cs)[136],
                                                const unsigned short* __restrict__ Wbt,
                                                unsigned short* __restrict__ xw, int row0,
                                                int wave, int lm, int q, int t) {
  const int r = wave >> 1, colb = (wave & 1) * 64;
  const unsigned short* Bt = Wbt + (size_t)r * HID * HID;
  s16x8 bfr[4][4];
#pragma unroll
  for (int kc = 0; kc < 4; ++kc) {
    const int ko = kc * 32 + q * 8;
#pragma unroll
    for (int ct = 0; ct < 4; ++ct)
      bfr[kc][ct] = *(const s16x8*)(Bt + (size_t)(colb + ct * 16 + lm) * HID + ko);
  }
  f32x4 acc[4][4];
#pragma unroll
  for (int a = 0; a < 4; ++a)
#pragma unroll
    for (int c = 0; c < 4; ++c) { f32x4 z = {0.f, 0.f, 0.f, 0.f}; acc[a][c] = z; }
#pragma unroll
  for (int kc = 0; kc < 4; ++kc) {
    const int ko = kc * 32 + q * 8;
#pragma unroll
    for (int rt = 0; rt < 4; ++rt) {
      s16x8 a = *(const s16x8*)&As[rt * 16 + lm][ko];
#pragma unroll
      for (int ct = 0; ct < 4; ++ct)
        acc[rt][ct] = __builtin_amdgcn_mfma_f32_16x16x32_bf16(a, bfr[kc][ct], acc[rt][ct], 0, 0, 0);
    }
  }
  __syncthreads();
#pragma unroll
  for (int rr = 0; rr < 2; ++rr) {
    if (r == rr) {
#pragma unroll
      for (int rt = 0; rt < 4; ++rt)
#pragma unroll
        for (int i = 0; i < 4; ++i) {
          int rloc = rt * 16 + q * 4 + i;
#pragma unroll
          for (int ct = 0; ct < 4; ++ct)
            Cs[rloc][colb + ct * 16 + lm] = f2bf_bits(acc[rt][ct][i]);
        }
    }
    __syncthreads();
    unsigned short* dst = xw + ((size_t)rr * NPAD + row0) * HID;
#pragma unroll
    for (int j = 0; j < 4; ++j) {
      int idx = j * 256 + t;                  // 1024 16B units
      int rw = idx >> 4, cb8 = (idx & 15) * 8;
      if (row0 + rw < N_NODES)
        *(s16x8*)(dst + (size_t)rw * HID + cb8) = *(const s16x8*)&Cs[rw][cb8];
    }
    __syncthreads();
  }
}

// qk body: wave w handles 16 rows [16w,16w+16) of As; writes qi4/kj4.
__device__ __forceinline__ void qk16_from_lds(unsigned short (*As)[136], unsigned short (*Cs)[136],
                                              const unsigned short* __restrict__ qkt_hi,
                                              const unsigned short* __restrict__ qkt_lo,
                                              float4* __restrict__ qi4, float4* __restrict__ kj4,
                                              int row0, int wave, int lane, int lm, int q) {
  s16x8 bhi[4], blo[4], af[4];
#pragma unroll
  for (int kc = 0; kc < 4; ++kc) {
    const int ko = kc * 32 + q * 8;
    bhi[kc] = *(const s16x8*)(qkt_hi + (size_t)lm * HID + ko);
    blo[kc] = *(const s16x8*)(qkt_lo + (size_t)lm * HID + ko);
    af[kc]  = *(const s16x8*)&As[wave * 16 + lm][ko];
  }
  f32x4 acc = {0.f, 0.f, 0.f, 0.f};
#pragma unroll
  for (int kc = 0; kc < 4; ++kc) {
    acc = __builtin_amdgcn_mfma_f32_16x16x32_bf16(af[kc], bhi[kc], acc, 0, 0, 0);
    acc = __builtin_amdgcn_mfma_f32_16x16x32_bf16(af[kc], blo[kc], acc, 0, 0, 0);
  }
  float (*Fs)[16][17] = (float(*)[16][17])&Cs[0][0];   // 4*16*17*4 = 17408 B
#pragma unroll
  for (int i = 0; i < 4; ++i)
    Fs[wave][lm][q * 4 + i] = acc[i];
  __syncthreads();
  if (lane < 16) {
    int n = row0 + wave * 16 + lane;
    if (n < N_NODES) {
      float4 v;
      v.x = Fs[wave][0][lane];  v.y = Fs[wave][1][lane];  v.z = Fs[wave][2][lane];  v.w = Fs[wave][3][lane];
      qi4[n] = v;
      v.x = Fs[wave][4][lane];  v.y = Fs[wave][5][lane];  v.z = Fs[wave][6][lane];  v.w = Fs[wave][7][lane];
      qi4[NPAD + n] = v;
      v.x = Fs[wave][8][lane];  v.y = Fs[wave][9][lane];  v.z = Fs[wave][10][lane]; v.w = Fs[wave][11][lane];
      kj4[n] = v;
      v.x = Fs[wave][12][lane]; v.y = Fs[wave][13][lane]; v.z = Fs[wave][14][lane]; v.w = Fs[wave][15][lane];
      kj4[NPAD + n] = v;
    }
  }
}

// ====== layer 0: cvt(x rows) + gemm_xw + qk, all row-local in one block ======
__global__ __launch_bounds__(256) void fused_l0_kernel(const void* __restrict__ x,
                                                       const unsigned short* __restrict__ Wbt,
                                                       unsigned short* __restrict__ xw,
                                                       const unsigned short* __restrict__ qkt_hi,
                                                       const unsigned short* __restrict__ qkt_lo,
                                                       float4* __restrict__ qi4,
                                                       float4* __restrict__ kj4,
                                                       const int* __restrict__ flags) {
  __shared__ unsigned short As[64][136];
  __shared__ unsigned short Cs[64][136];
  const int t = threadIdx.x;
  const int wave = t >> 6, lane = t & 63;
  const int lm = lane & 15, q = lane >> 4;
  const int row0 = blockIdx.x * 64;
  // stage + convert 64 input rows -> bf16 LDS (pad rows zero: x has only N_NODES rows)
  if (flags[0]) {
    const float* xf = (const float*)x;
#pragma unroll
    for (int j = 0; j < 4; ++j) {
      int idx = j * 256 + t;
      int rw = idx >> 4, cb8 = (idx & 15) * 8;
      s16x8 o = {0, 0, 0, 0, 0, 0, 0, 0};
      if (row0 + rw < N_NODES) {
        const float4* s4 = (const float4*)(xf + (size_t)(row0 + rw) * HID + cb8);
        float4 a = s4[0], b = s4[1];
        o[0] = (short)f2bf_bits(a.x); o[1] = (short)f2bf_bits(a.y);
        o[2] = (short)f2bf_bits(a.z); o[3] = (short)f2bf_bits(a.w);
        o[4] = (short)f2bf_bits(b.x); o[5] = (short)f2bf_bits(b.y);
        o[6] = (short)f2bf_bits(b.z); o[7] = (short)f2bf_bits(b.w);
      }
      *(s16x8*)&As[rw][cb8] = o;
    }
  } else {
    const unsigned short* xb = (const unsigned short*)x;
#pragma unroll
    for (int j = 0; j < 4; ++j) {
      int idx = j * 256 + t;
      int rw = idx >> 4, cb8 = (idx & 15) * 8;
      s16x8 o = {0, 0, 0, 0, 0, 0, 0, 0};
      if (row0 + rw < N_NODES)
        o = *(const s16x8*)(xb + (size_t)(row0 + rw) * HID + cb8);
      *(s16x8*)&As[rw][cb8] = o;
    }
  }
  __syncthreads();
  gemm64_from_lds(As, Cs, Wbt, xw, row0, wave, lm, q, t);
  qk16_from_lds(As, Cs, qkt_hi, qkt_lo, qi4, kj4, row0, wave, lane, lm, q);
}

// ====== mid: proj(l0) + gemm_xw(l1) + qk(l1), row-local, no hb round-trip ======
__global__ __launch_bounds__(256) void fused_mid_kernel(const unsigned short* __restrict__ aggb,
                                                        const unsigned short* __restrict__ pWTb,
                                                        const float* __restrict__ bo,
                                                        const unsigned short* __restrict__ Wbt1,
                                                        unsigned short* __restrict__ xw,
                                                        const unsigned short* __restrict__ qkt_hi,
                                                        const unsigned short* __restrict__ qkt_lo,
                                                        float4* __restrict__ qi4,
                                                        float4* __restrict__ kj4) {
  __shared__ unsigned short As[64][136];
  __shared__ unsigned short Cs[64][136];
  const int t = threadIdx.x;
  const int wave = t >> 6, lane = t & 63;
  const int lm = lane & 15, q = lane >> 4;
  const int row0 = blockIdx.x * 64;
  // ---- proj: out = elu(agg @ pWT + bo); wave = (rowhalf h, colpanel) 32x64 ----
  const int h = wave >> 1;
  const int colb = (wave & 1) * 64;
  s16x8 bfr[4][4];
#pragma unroll
  for (int kc = 0; kc < 4; ++kc) {
    const int ko = kc * 32 + q * 8;
#pragma unroll
    for (int ct = 0; ct < 4; ++ct)
      bfr[kc][ct] = *(const s16x8*)(pWTb + (size_t)(colb + ct * 16 + lm) * HID + ko);
  }
  const unsigned short* gsrc = aggb + (size_t)row0 * HID;
#pragma unroll
  for (int j = 0; j < 4; ++j) {
    int idx = j * 256 + t;
    *(s16x8*)&As[idx >> 4][(idx & 15) * 8] = *(const s16x8*)(gsrc + idx * 8);
  }
  __syncthreads();
  f32x4 pacc[2][4];
#pragma unroll
  for (int a = 0; a < 2; ++a)
#pragma unroll
    for (int c = 0; c < 4; ++c) { f32x4 z = {0.f, 0.f, 0.f, 0.f}; pacc[a][c] = z; }
#pragma unroll
  for (int kc = 0; kc < 4; ++kc) {
    const int ko = kc * 32 + q * 8;
#pragma unroll
    for (int rt = 0; rt < 2; ++rt) {
      s16x8 a = *(const s16x8*)&As[(2 * h + rt) * 16 + lm][ko];
#pragma unroll
      for (int ct = 0; ct < 4; ++ct)
        pacc[rt][ct] = __builtin_amdgcn_mfma_f32_16x16x32_bf16(a, bfr[kc][ct], pacc[rt][ct], 0, 0, 0);
    }
  }
  __syncthreads();                            // As reads done
  // epilogue: elu + bias -> back into As (becomes layer-1 input rows)
#pragma unroll
  for (int rt = 0; rt < 2; ++rt)
#pragma unroll
    for (int i = 0; i < 4; ++i) {
      int rloc = (2 * h + rt) * 16 + q * 4 + i;
#pragma unroll
      for (int ct = 0; ct < 4; ++ct) {
        int o = colb + ct * 16 + lm;
        As[rloc][o] = f2bf_bits(elu(pacc[rt][ct][i] + bo[o]));
      }
    }
  __syncthreads();
  // ---- gemm_xw(l1) + qk(l1) on the fresh rows ----
  gemm64_from_lds(As, Cs, Wbt1, xw, row0, wave, lm, q, t);
  qk16_from_lds(As, Cs, qkt_hi, qkt_lo, qi4, kj4, row0, wave, lane, lm, q);
}

// ====== fused edge: big (deg>16) FIRST (long poles), then quad ======
__global__ __launch_bounds__(256) void edge_all_kernel(
    const int* __restrict__ rowstart, const int* __restrict__ eord,
    const float4* __restrict__ qi4, const float4* __restrict__ kj4,
    const unsigned short* __restrict__ xw, unsigned short* __restrict__ aggb,
    const int* __restrict__ nq, const int* __restrict__ nw,
    const int* __restrict__ bcnt) {
  __shared__ volatile float wbuf[1152];       // quad: [16][4][17]=1088  big: [4][4][72]=1152
  const int t = threadIdx.x;
  const int wave = t >> 6, lane = t & 63;
  if (blockIdx.x >= GB_BIG) {
    // ---- quad: 4 nodes/wave, 16 lanes/node, 8 ch/lane ----
    const int g = lane >> 4, li = lane & 15;
    const int idx = (blockIdx.x - GB_BIG) * 16 + wave * 4 + g;
    const int cq = bcnt[0];
    const bool act = idx < cq;
    const int n = act ? nq[idx] : 0;
    const int start = rowstart[n];
    const int dg = act ? (rowstart[n + 1] - start) : 0;
    int p = 0;
    float w0 = 0.f, w1 = 0.f, w2 = 0.f, w3 = 0.f;
    if (li < dg) {
      p = eord[start + li];
      int s = p & 0xffff, r = p >> 16;
      float4 k4 = kj4[r ? (NPAD + s) : s];
      float4 q4 = r ? qi4[NPAD + n] : qi4[n];
      w0 = __expf(fminf(lrelu(q4.x + k4.x), 85.f));
      w1 = __expf(fminf(lrelu(q4.y + k4.y), 85.f));
      w2 = __expf(fminf(lrelu(q4.z + k4.z), 85.f));
      w3 = __expf(fminf(lrelu(q4.w + k4.w), 85.f));
    }
    const int wg = (wave << 2) | g;
    volatile float* wls = &wbuf[wg * 68];     // [4][17]
    wls[0 * 17 + li] = w0; wls[1 * 17 + li] = w1;
    wls[2 * 17 + li] = w2; wls[3 * 17 + li] = w3;
    float s0 = w0, s1 = w1, s2 = w2, s3 = w3;
#pragma unroll
    for (int off = 8; off > 0; off >>= 1) {
      s0 += __shfl_xor(s0, off); s1 += __shfl_xor(s1, off);
      s2 += __shfl_xor(s2, off); s3 += __shfl_xor(s3, off);
    }
    const int hh = li >> 2;
    float ssel = hh == 0 ? s0 : hh == 1 ? s1 : hh == 2 ? s2 : s3;
    float a0 = 0.f, a1 = 0.f, a2 = 0.f, a3 = 0.f, a4 = 0.f, a5 = 0.f, a6 = 0.f, a7 = 0.f;
    volatile const float* wrh = &wls[hh * 17];
    const int co = li * 8;
    const int gbase = lane & 48;
#pragma unroll 1
    for (int e0 = 0; e0 < dg; e0 += 4) {
      int pe[4];
      uint4 v[4];
#pragma unroll
      for (int u = 0; u < 4; ++u) {
        int e = e0 + u;
        pe[u] = __shfl(p, gbase + (e < dg ? e : 0));
      }
#pragma unroll
      for (int u = 0; u < 4; ++u)
        v[u] = *(const uint4*)(xw + ((size_t)((pe[u] & 0xffff) + (pe[u] >> 16) * NPAD) << 7) + co);
#pragma unroll
      for (int u = 0; u < 4; ++u) {
        int e = e0 + u;
        float we = (e < dg) ? wrh[e] : 0.f;
        a0 = fmaf(lo_f(v[u].x), we, a0); a1 = fmaf(hi_f(v[u].x), we, a1);
        a2 = fmaf(lo_f(v[u].y), we, a2); a3 = fmaf(hi_f(v[u].y), we, a3);
        a4 = fmaf(lo_f(v[u].z), we, a4); a5 = fmaf(hi_f(v[u].z), we, a5);
        a6 = fmaf(lo_f(v[u].w), we, a6); a7 = fmaf(hi_f(v[u].w), we, a7);
      }
    }
    if (act) {
      float inv = 1.f / (ssel + 1e-16f);
      uint4 o;
      o.x = (unsigned)f2bf_bits(a0 * inv) | ((unsigned)f2bf_bits(a1 * inv) << 16);
      o.y = (unsigned)f2bf_bits(a2 * inv) | ((unsigned)f2bf_bits(a3 * inv) << 16);
      o.z = (unsigned)f2bf_bits(a4 * inv) | ((unsigned)f2bf_bits(a5 * inv) << 16);
      o.w = (unsigned)f2bf_bits(a6 * inv) | ((unsigned)f2bf_bits(a7 * inv) << 16);
      *(uint4*)(aggb + ((size_t)n << 7) + co) = o;
    }
  } else {
    // ---- big: one wave per node ----
    const int idx = blockIdx.x * 4 + wave;
    const int cw = bcnt[1];
    if (idx >= cw) return;
    const int n = nw[idx];
    unsigned* outp = (unsigned*)(aggb + ((size_t)n << 7)) + lane;
    const int start = rowstart[n];
    const int deg = rowstart[n + 1] - start;
    const int hh = lane >> 4;
    const int ch2 = lane << 1;
    float2 acc = {0.f, 0.f};
    float ssel;
    volatile float* wls = &wbuf[wave * 288];  // [4][72]
    if (deg <= 64) {
      int p = 0;
      float w0 = 0.f, w1 = 0.f, w2 = 0.f, w3 = 0.f;
      if (lane < deg) {
        p = eord[start + lane];
        int s = p & 0xffff, r = p >> 16;
        float4 k4 = kj4[r ? (NPAD + s) : s];
        float4 q4 = r ? qi4[NPAD + n] : qi4[n];
        w0 = __expf(fminf(lrelu(q4.x + k4.x), 85.f));
        w1 = __expf(fminf(lrelu(q4.y + k4.y), 85.f));
        w2 = __expf(fminf(lrelu(q4.z + k4.z), 85.f));
        w3 = __expf(fminf(lrelu(q4.w + k4.w), 85.f));
      }
      float s0 = w0, s1 = w1, s2 = w2, s3 = w3;
#pragma unroll
      for (int off = 32; off > 0; off >>= 1) {
        s0 += __shfl_xor(s0, off); s1 += __shfl_xor(s1, off);
        s2 += __shfl_xor(s2, off); s3 += __shfl_xor(s3, off);
      }
      ssel = hh == 0 ? s0 : hh == 1 ? s1 : hh == 2 ? s2 : s3;
      wls[0 * 72 + lane] = w0;
      wls[1 * 72 + lane] = w1;
      wls[2 * 72 + lane] = w2;
      wls[3 * 72 + lane] = w3;
      volatile const float* wrh = &wls[hh * 72];
      const int degp = (deg + 15) & ~15;
#pragma unroll 1
      for (int e = 0; e < degp; e += 16) {
        int pp[16];
        unsigned vv[16];
#pragma unroll
        for (int u = 0; u < 16; ++u)
          pp[u] = __builtin_amdgcn_readlane(p, e + u);
#pragma unroll
        for (int u = 0; u < 16; ++u)
          vv[u] = *(const unsigned*)(xw + ((size_t)((pp[u] & 0xffff) + (pp[u] >> 16) * NPAD) << 7) + ch2);
#pragma unroll
        for (int u = 0; u < 16; ++u) {
          float we = wrh[e + u];
          acc.x = fmaf(lo_f(vv[u]), we, acc.x);
          acc.y = fmaf(hi_f(vv[u]), we, acc.y);
        }
      }
    } else {
      const float4 q0 = qi4[n], q1 = qi4[NPAD + n];
      float4 m = make_float4(-1e30f, -1e30f, -1e30f, -1e30f);
      for (int e = start; e < start + deg; ++e) {
        int pe = eord[e];
        int s = pe & 0xffff, r = pe >> 16;
        float4 k4 = kj4[(size_t)r * NPAD + s];
        float4 q4 = r ? q1 : q0;
        m.x = fmaxf(m.x, lrelu(q4.x + k4.x)); m.y = fmaxf(m.y, lrelu(q4.y + k4.y));
        m.z = fmaxf(m.z, lrelu(q4.z + k4.z)); m.w = fmaxf(m.w, lrelu(q4.w + k4.w));
      }
      float4 sv = make_float4(0.f, 0.f, 0.f, 0.f);
      for (int e = start; e < start + deg; ++e) {
        int pe = eord[e];
        int s = pe & 0xffff, r = pe >> 16;
        float4 k4 = kj4[(size_t)r * NPAD + s];
        float4 q4 = r ? q1 : q0;
        float w0 = __expf(lrelu(q4.x + k4.x) - m.x);
        float w1 = __expf(lrelu(q4.y + k4.y) - m.y);
        float w2 = __expf(lrelu(q4.z + k4.z) - m.z);
        float w3 = __expf(lrelu(q4.w + k4.w) - m.w);
        sv.x += w0; sv.y += w1; sv.z += w2; sv.w += w3;
        float we = hh == 0 ? w0 : hh == 1 ? w1 : hh == 2 ? w2 : w3;
        unsigned v = *(const unsigned*)(xw + (((size_t)r * NPAD + s) << 7) + ch2);
        acc.x = fmaf(lo_f(v), we, acc.x);
        acc.y = fmaf(hi_f(v), we, acc.y);
      }
      ssel = hh == 0 ? sv.x : hh == 1 ? sv.y : hh == 2 ? sv.z : sv.w;
    }
    float inv = 1.f / (ssel + 1e-16f);
    *outp = (unsigned)f2bf_bits(acc.x * inv) | ((unsigned)f2bf_bits(acc.y * inv) << 16);
  }
}

// ---- final proj: 64 rows/block, 4 waves, writes d_out ----
__global__ __launch_bounds__(256) void proj_final(const unsigned short* __restrict__ aggb,
                                                  const unsigned short* __restrict__ pWTb,
                                                  const float* __restrict__ bo,
                                                  void* __restrict__ dout,
                                                  const int* __restrict__ flags) {
  __shared__ unsigned short As[64][136];
  const int t = threadIdx.x;
  const int wave = t >> 6, lane = t & 63;
  const int row0 = blockIdx.x * 64;
  const int h = wave >> 1;
  const int colb = (wave & 1) * 64;
  const int lm = lane & 15, q = lane >> 4;
  s16x8 bfr[4][4];
#pragma unroll
  for (int kc = 0; kc < 4; ++kc) {
    const int ko = kc * 32 + q * 8;
#pragma unroll
    for (int ct = 0; ct < 4; ++ct)
      bfr[kc][ct] = *(const s16x8*)(pWTb + (size_t)(colb + ct * 16 + lm) * HID + ko);
  }
  const unsigned short* gsrc = aggb + (size_t)row0 * HID;
#pragma unroll
  for (int j = 0; j < 4; ++j) {
    int idx = j * 256 + t;
    *(s16x8*)&As[idx >> 4][(idx & 15) * 8] = *(const s16x8*)(gsrc + idx * 8);
  }
  __syncthreads();
  f32x4 acc[2][4];
#pragma unroll
  for (int a = 0; a < 2; ++a)
#pragma unroll
    for (int c = 0; c < 4; ++c) { f32x4 z = {0.f, 0.f, 0.f, 0.f}; acc[a][c] = z; }
#pragma unroll
  for (int kc = 0; kc < 4; ++kc) {
    const int ko = kc * 32 + q * 8;
#pragma unroll
    for (int rt = 0; rt < 2; ++rt) {
      s16x8 a = *(const s16x8*)&As[(2 * h + rt) * 16 + lm][ko];
#pragma unroll
      for (int ct = 0; ct < 4; ++ct)
        acc[rt][ct] = __builtin_amdgcn_mfma_f32_16x16x32_bf16(a, bfr[kc][ct], acc[rt][ct], 0, 0, 0);
    }
  }
  __syncthreads();
  if (!flags[0]) {
    unsigned short* dstp = (unsigned short*)dout;
#pragma unroll
    for (int rt = 0; rt < 2; ++rt)
#pragma unroll
      for (int i = 0; i < 4; ++i) {
        int rloc = (2 * h + rt) * 16 + q * 4 + i;
#pragma unroll
        for (int ct = 0; ct < 4; ++ct) {
          int o = colb + ct * 16 + lm;
          As[rloc][o] = f2bf_bits(elu(acc[rt][ct][i] + bo[o]));
        }
      }
    __syncthreads();
#pragma unroll
    for (int j = 0; j < 4; ++j) {
      int idx = j * 256 + t;
      int rw = idx >> 4, cb8 = (idx & 15) * 8;
      if (row0 + rw < N_NODES)
        *(s16x8*)(dstp + (size_t)(row0 + rw) * HID + cb8) = *(const s16x8*)&As[rw][cb8];
    }
  } else {
    float* fdst = (float*)dout;
    float (*Fs)[132] = (float(*)[132])&As[0][0];   // 32*132*4 = 16896 B
#pragma unroll
    for (int h2 = 0; h2 < 2; ++h2) {
      if (h == h2) {
#pragma unroll
        for (int rt = 0; rt < 2; ++rt)
#pragma unroll
          for (int i = 0; i < 4; ++i) {
            int rloc = rt * 16 + q * 4 + i;
#pragma unroll
            for (int ct = 0; ct < 4; ++ct) {
              int o = colb + ct * 16 + lm;
              Fs[rloc][o] = elu(acc[rt][ct][i] + bo[o]);
            }
          }
      }
      __syncthreads();
#pragma unroll
      for (int j = 0; j < 4; ++j) {
        int idx = j * 256 + t;
        int rw = idx >> 5, cb4 = (idx & 31) * 4;
        if (row0 + h2 * 32 + rw < N_NODES)
          *(float4*)(fdst + (size_t)(row0 + h2 * 32 + rw) * HID + cb4) = *(const float4*)&Fs[rw][cb4];
      }
      __syncthreads();
    }
  }
}

extern "C" void kernel_launch(void* const* d_in, const int* in_sizes, int n_in,
                              void* d_out, int out_size, void* d_ws, size_t ws_size,
                              hipStream_t stream) {
  const void* x     = d_in[0];
  const int*  eidx  = (const int*)d_in[1];
  const int*  etype = (const int*)d_in[2];
  const int iW[2] = {3, 9}, iQ[2] = {4, 10}, iK[2] = {5, 11}, icb[2] = {6, 12}, ipW[2] = {7, 13}, ipb[2] = {8, 14};

  float* ws = (float*)d_ws;
  size_t off = 0;
  int*   flags = (int*)(ws + off); off += 16;
  unsigned short* xw   = (unsigned short*)(ws + off); off += (size_t)NPAD * HID;       // [2][NPAD][128] bf16
  float* qi   = ws + off; off += (size_t)2 * NPAD * HEADS;
  float* kj   = ws + off; off += (size_t)2 * NPAD * HEADS;
  unsigned short* aggb = (unsigned short*)(ws + off); off += (size_t)NPAD * HID / 2;
  int* dstA = (int*)(ws + off); off += E_EDGES;
  int* pk   = (int*)(ws + off); off += E_EDGES;
  int* eord = (int*)(ws + off); off += E_EDGES;
  int* deg  = (int*)(ws + off); off += NPAD;        // deg|cnt|bcnt contiguous for one zero pass
  int* cnt  = (int*)(ws + off); off += NPAD;
  int* bcnt = (int*)(ws + off); off += 16;
  int* excl = (int*)(ws + off); off += NPAD;
  int* rowstart = (int*)(ws + off); off += NPAD + 16;
  int* bsum  = (int*)(ws + off); off += 256;
  int* nq   = (int*)(ws + off); off += NPAD;
  int* nwl  = (int*)(ws + off); off += NPAD;
  unsigned short* Wbt   = (unsigned short*)(ws + off); off += (size_t)2 * 2 * HID * HID / 2;
  unsigned short* pWTb2 = (unsigned short*)(ws + off); off += (size_t)2 * HID * HID / 2;
  unsigned short* qkt_hi = (unsigned short*)(ws + off); off += (size_t)2 * 16 * HID / 2;
  unsigned short* qkt_lo = (unsigned short*)(ws + off); off += (size_t)2 * 16 * HID / 2;
  float* Qf  = ws + off; off += 2 * HID * HEADS;
  float* Kf  = ws + off; off += 2 * HID * HEADS;
  float* cbf = ws + off; off += 2 * HID;
  float* pbf = ws + off; off += 2 * HID;
  float* bo2 = ws + off; off += 2 * HID;

  // D1: detect + zero deg|cnt|bcnt
  detect_zero_kernel<<<(2 * NPAD + 16 + 255) / 256, 256, 0, stream>>>((const unsigned short*)x, eidx, flags, deg, 2 * NPAD + 16);

  // D2: converts (idx+hist | wt | params)  (x conversion moved into fused_l0)
  {
    P8 tab;
    float* base = ws;
    for (int l = 0; l < 2; ++l) {
      tab.src[l * 4 + 0] = d_in[iQ[l]];  tab.dstoff[l * 4 + 0] = (int)(Qf - base) + l * HID * HEADS;  tab.n[l * 4 + 0] = HID * HEADS;
      tab.src[l * 4 + 1] = d_in[iK[l]];  tab.dstoff[l * 4 + 1] = (int)(Kf - base) + l * HID * HEADS;  tab.n[l * 4 + 1] = HID * HEADS;
      tab.src[l * 4 + 2] = d_in[icb[l]]; tab.dstoff[l * 4 + 2] = (int)(cbf - base) + l * HID;         tab.n[l * 4 + 2] = HID;
      tab.src[l * 4 + 3] = d_in[ipb[l]]; tab.dstoff[l * 4 + 3] = (int)(pbf - base) + l * HID;         tab.n[l * 4 + 3] = HID;
    }
    cvt_all_kernel<<<GB_IDX + GB_WT + 2, 256, 0, stream>>>(eidx, etype, dstA, pk, deg,
                                                           d_in[iW[0]], d_in[iW[1]], Wbt,
                                                           tab, ws, flags);
  }

  // D3: scan stage 1 + bucketing
  scan1_bucket_kernel<<<SCAN_B + SCAN_B, 256, 0, stream>>>(deg, excl, bsum, bcnt, nq, nwl);

  // D4: scan stages 2+3 + param folds
  scan23_prep_kernel<<<SCAN_B + 2 + 64, 256, 0, stream>>>(excl, bsum, rowstart,
                                                          Wbt, Qf, Kf, qkt_hi, qkt_lo,
                                                          d_in[ipW[0]], d_in[ipW[1]], cbf, pbf, pWTb2, bo2, flags);

  // D5: counting-sort scatter
  scatter_kernel<<<(E_EDGES + 255) / 256, 256, 0, stream>>>(dstA, pk, rowstart, cnt, eord);

  const int RB = NPAD / 64;   // 782 row-blocks
  // layer 0: cvt + gemm + qk fused
  fused_l0_kernel<<<RB, 256, 0, stream>>>(x, Wbt, xw, qkt_hi, qkt_lo,
                                          (float4*)qi, (float4*)kj, flags);
  edge_all_kernel<<<GB_BIG + GB_QUAD, 256, 0, stream>>>(rowstart, eord, (const float4*)qi, (const float4*)kj,
                                                        xw, aggb, nq, nwl, bcnt);
  // proj(l0) + gemm(l1) + qk(l1) fused
  fused_mid_kernel<<<RB, 256, 0, stream>>>(aggb, pWTb2, bo2, Wbt + (size_t)2 * HID * HID, xw,
                                           qkt_hi + (size_t)16 * HID, qkt_lo + (size_t)16 * HID,
                                           (float4*)qi, (float4*)kj);
  edge_all_kernel<<<GB_BIG + GB_QUAD, 256, 0, stream>>>(rowstart, eord, (const float4*)qi, (const float4*)kj,
                                                        xw, aggb, nq, nwl, bcnt);
  // final proj -> d_out
  proj_final<<<RB, 256, 0, stream>>>(aggb, pWTb2 + (size_t)HID * HID, bo2 + HID, d_out, flags);
}